// Round 2
// baseline (1906.506 us; speedup 1.0000x reference)
//
#include <hip/hip_runtime.h>
#include <cstdio>

#define B_ 32
#define S_ 512
#define D_ 1024
#define H_ 512
#define K_ 16
#define L_ 16
#define NT_ 16
#define NSEQ 512      // B*K
#define XROWS 8192    // NSEQ*L
#define G4H 2048      // 4*H
#define OUTC 2080

typedef unsigned short u16;
typedef __bf16 bf16x8 __attribute__((ext_vector_type(8)));
typedef float f32x4 __attribute__((ext_vector_type(4)));

__device__ inline u16 f2b(float f) {
  union { float f; unsigned u; } x; x.f = f;
  unsigned r = x.u + 0x7FFFu + ((x.u >> 16) & 1u);
  return (u16)(r >> 16);
}
__device__ inline float sigf(float x) { return 1.0f / (1.0f + expf(-x)); }
__device__ inline float wredsum(float v) {
#pragma unroll
  for (int off = 32; off > 0; off >>= 1) v += __shfl_xor(v, off);
  return v;
}

// ---------------- casts ----------------
__global__ __launch_bounds__(256) void cast_kernel(const float* __restrict__ in,
                                                   u16* __restrict__ out, int n) {
  int i = blockIdx.x * 256 + threadIdx.x;
  if (i < n) out[i] = f2b(in[i]);
}

// split f32 into hi+lo bf16 (bf16x3 emulation)
__global__ __launch_bounds__(256) void split_kernel(const float* __restrict__ in,
                                                    u16* __restrict__ hi,
                                                    u16* __restrict__ lo, int n) {
  int i = blockIdx.x * 256 + threadIdx.x;
  if (i >= n) return;
  float x = in[i];
  u16 h = f2b(x);
  union { unsigned u; float f; } c; c.u = ((unsigned)h) << 16;
  hi[i] = h;
  lo[i] = f2b(x - c.f);
}

// gather span rows from hidden_layers, cast to bf16: Xbf[(n*L+t)][d]
__global__ __launch_bounds__(256) void gather_cast_kernel(const float* __restrict__ hidden,
                                                          const int* __restrict__ span_idx,
                                                          u16* __restrict__ Xbf) {
  int row = blockIdx.x;          // n*L + t
  int n = row >> 4;              // L = 16
  int b = n >> 4;                // K = 16
  int s = span_idx[row];
  const float* src = hidden + ((size_t)b * S_ + s) * D_;
  u16* dst = Xbf + (size_t)row * D_;
  for (int d = threadIdx.x; d < D_; d += 256) dst[d] = f2b(src[d]);
}

// ---------------- generic bf16 GEMM: C(MxN) = A(MxK) * B(NxK)^T ----------------
// flags: 1 = tanh, 2 = out bf16 (Cb), 4 = accumulate into Cf
__global__ __launch_bounds__(256) void gemm_bt_kernel(
    const u16* __restrict__ A, const u16* __restrict__ Bm,
    float* __restrict__ Cf, u16* __restrict__ Cb,
    const float* __restrict__ bias,
    int M, int N, int Kd, int ldc, int flags) {
  __shared__ u16 As[128][40];
  __shared__ u16 Bs[128][40];
  const int tid = threadIdx.x;
  const int bm = blockIdx.y * 128, bn = blockIdx.x * 128;
  const int wave = tid >> 6, lane = tid & 63;
  const int wm = (wave >> 1) * 64, wn = (wave & 1) * 64;
  f32x4 acc[4][4] = {};

  const int lr = tid >> 2;          // 0..63
  const int lk = (tid & 3) * 8;     // 0,8,16,24
  const int fr = lane & 15;
  const int kg = (lane >> 4) * 8;

  for (int k0 = 0; k0 < Kd; k0 += 32) {
#pragma unroll
    for (int half = 0; half < 2; ++half) {
      int row = lr + half * 64;
      uint4 va = {0u, 0u, 0u, 0u};
      int ga = bm + row;
      if (ga < M) va = *reinterpret_cast<const uint4*>(A + (size_t)ga * Kd + k0 + lk);
      *reinterpret_cast<uint4*>(&As[row][lk]) = va;
      uint4 vb = {0u, 0u, 0u, 0u};
      int gb = bn + row;
      if (gb < N) vb = *reinterpret_cast<const uint4*>(Bm + (size_t)gb * Kd + k0 + lk);
      *reinterpret_cast<uint4*>(&Bs[row][lk]) = vb;
    }
    __syncthreads();
    bf16x8 af[4], bfr[4];
#pragma unroll
    for (int m = 0; m < 4; ++m)
      af[m] = *reinterpret_cast<const bf16x8*>(&As[wm + m * 16 + fr][kg]);
#pragma unroll
    for (int n = 0; n < 4; ++n)
      bfr[n] = *reinterpret_cast<const bf16x8*>(&Bs[wn + n * 16 + fr][kg]);
#pragma unroll
    for (int m = 0; m < 4; ++m)
#pragma unroll
      for (int n = 0; n < 4; ++n)
        acc[m][n] = __builtin_amdgcn_mfma_f32_16x16x32_bf16(af[m], bfr[n], acc[m][n], 0, 0, 0);
    __syncthreads();
  }

  const int ci = lane & 15;
  const int r0 = (lane >> 4) * 4;
#pragma unroll
  for (int m = 0; m < 4; ++m) {
#pragma unroll
    for (int n = 0; n < 4; ++n) {
      int col = bn + wn + n * 16 + ci;
#pragma unroll
      for (int r = 0; r < 4; ++r) {
        int row = bm + wm + m * 16 + r0 + r;
        if (row < M && col < N) {
          size_t idx = (size_t)row * ldc + col;
          float v = acc[m][n][r];
          if (flags & 4) v += Cf[idx];
          if (bias) v += bias[col];
          if (flags & 1) v = tanhf(v);
          if (flags & 2) Cb[idx] = f2b(v);
          else Cf[idx] = v;
        }
      }
    }
  }
}

// ---------------- LSTM gate/state update ----------------
__global__ __launch_bounds__(256) void lstm_gate_kernel(
    const float* __restrict__ Graw,   // (XROWS, 4H): x @ Wih^T
    const float* __restrict__ hW,     // (NSEQ, 4H): h @ Whh^T
    const float* __restrict__ bih, const float* __restrict__ bhh,
    const float* __restrict__ mask,   // (NSEQ, L)
    float* __restrict__ h, float* __restrict__ c,   // (NSEQ, H)
    u16* __restrict__ hbf,            // (NSEQ, H)
    float* __restrict__ sf,           // (NSEQ, 2H), +=
    int treal, int coloff) {
  int n = blockIdx.x;
  float m = mask[n * L_ + treal];
  const float* g0 = Graw + ((size_t)n * L_ + treal) * G4H;
  const float* hw = hW + (size_t)n * G4H;
  for (int j = threadIdx.x; j < H_; j += 256) {
    float gi = g0[j]            + hw[j]            + bih[j]            + bhh[j];
    float gf = g0[H_ + j]       + hw[H_ + j]       + bih[H_ + j]       + bhh[H_ + j];
    float gg = g0[2 * H_ + j]   + hw[2 * H_ + j]   + bih[2 * H_ + j]   + bhh[2 * H_ + j];
    float go = g0[3 * H_ + j]   + hw[3 * H_ + j]   + bih[3 * H_ + j]   + bhh[3 * H_ + j];
    int idx = n * H_ + j;
    float co = c[idx], ho = h[idx];
    float cn = sigf(gf) * co + sigf(gi) * tanhf(gg);
    float hn = sigf(go) * tanhf(cn);
    float hnew = m * hn + (1.0f - m) * ho;
    float cnew = m * cn + (1.0f - m) * co;
    h[idx] = hnew; c[idx] = cnew;
    hbf[idx] = f2b(hnew);
    sf[(size_t)n * 1024 + coloff + j] += hnew * m;
  }
}

// ---------------- slot_feats copy into out cols [0,1024) ----------------
__global__ __launch_bounds__(256) void copy_sf_kernel(const float* __restrict__ sf,
                                                      float* __restrict__ out) {
  int bk = blockIdx.x;
  for (int d = threadIdx.x; d < 1024; d += 256)
    out[(size_t)bk * OUTC + d] = sf[(size_t)bk * 1024 + d];
}

// ---------------- attention scores ----------------
__global__ __launch_bounds__(256) void attn_kernel(
    const float* __restrict__ sf, const float* __restrict__ hidden,
    const int* __restrict__ sstart, const int* __restrict__ send,
    const int* __restrict__ len, float* __restrict__ attn) {
  int bk = blockIdx.x;
  int b = bk >> 4;
  __shared__ float sfl[1024];
  for (int d = threadIdx.x; d < 1024; d += 256) sfl[d] = sf[(size_t)bk * 1024 + d];
  __syncthreads();
  int st = sstart[bk], en = send[bk], ln = len[b];
  for (int s = threadIdx.x; s < S_; s += 256) {
    bool cm = (s < st) || ((s > en) && (s < ln));
    float a = 0.f;
    if (cm) {
      const float* hp = hidden + ((size_t)b * S_ + s) * D_;
      for (int d = 0; d < D_; ++d) a += sfl[d] * hp[d];
    }
    attn[(size_t)bk * S_ + s] = cm ? a : 0.f;
  }
}

// ---------------- context, writes out cols [1024,2048) ----------------
__global__ __launch_bounds__(256) void context_kernel(
    const float* __restrict__ attn, const float* __restrict__ hidden,
    float* __restrict__ out) {
  int bk = blockIdx.x;
  int b = bk >> 4;
  float acc[4] = {0.f, 0.f, 0.f, 0.f};
  for (int s = 0; s < S_; ++s) {
    float a = attn[(size_t)bk * S_ + s];
    if (a != 0.f) {
      const float* hp = hidden + ((size_t)b * S_ + s) * D_;
#pragma unroll
      for (int q = 0; q < 4; ++q) acc[q] += a * hp[threadIdx.x + q * 256];
    }
  }
#pragma unroll
  for (int q = 0; q < 4; ++q)
    out[(size_t)bk * OUTC + 1024 + threadIdx.x + q * 256] = acc[q];
}

// ---------------- target norms ----------------
__global__ __launch_bounds__(64) void tnorm_kernel(const float* __restrict__ t_cat,
                                                   float* __restrict__ tn) {
  int t = blockIdx.x, lane = threadIdx.x;
  float p = 0.f;
  for (int j = lane; j < 2048; j += 64) { float v = t_cat[t * 2048 + j]; p += v * v; }
  p = wredsum(p);
  if (lane == 0) tn[t] = fmaxf(sqrtf(p), 1e-8f);
}

// ---------------- labels: out cols [2048,2080) ----------------
__global__ __launch_bounds__(64) void labels_kernel(
    const float* __restrict__ s_cat, const float* __restrict__ t_cat,
    const float* __restrict__ tn, const int* __restrict__ src_ids,
    float* __restrict__ out) {
  int bk = blockIdx.x, lane = threadIdx.x;
  const float* srow = s_cat + (size_t)bk * 2048;
  float np = 0.f;
  float dots[16];
#pragma unroll
  for (int t = 0; t < 16; ++t) dots[t] = 0.f;
  for (int j = lane; j < 2048; j += 64) {
    float sv = srow[j];
    np += sv * sv;
#pragma unroll
    for (int t = 0; t < 16; ++t) dots[t] += sv * t_cat[t * 2048 + j];
  }
  np = wredsum(np);
#pragma unroll
  for (int t = 0; t < 16; ++t) dots[t] = wredsum(dots[t]);
  float sn = fmaxf(sqrtf(np), 1e-8f);
  float ssum = 0.f;
  float sims[16];
#pragma unroll
  for (int t = 0; t < 16; ++t) { sims[t] = dots[t] / (sn * tn[t]); ssum += sims[t]; }
  float scale = 0.9f / ssum;
  if (lane < 16) {
    out[(size_t)bk * OUTC + 2064 + lane] = sims[lane] * scale;
  } else if (lane < 32) {
    int t2 = lane - 16;
    out[(size_t)bk * OUTC + 2048 + t2] = (src_ids[bk] == t2) ? 0.1f : 0.f;
  }
}

// =======================================================================
extern "C" void kernel_launch(void* const* d_in, const int* in_sizes, int n_in,
                              void* d_out, int out_size, void* d_ws, size_t ws_size,
                              hipStream_t stream) {
  const float* hidden    = (const float*)d_in[0];
  const int*   span_idx  = (const int*)d_in[1];
  const float* span_mask = (const float*)d_in[2];
  const int*   span_start= (const int*)d_in[3];
  const int*   span_end  = (const int*)d_in[4];
  const int*   length    = (const int*)d_in[5];
  const float* slot_emb  = (const float*)d_in[6];
  const float* tgt       = (const float*)d_in[7];
  const int*   src_ids   = (const int*)d_in[8];
  const float* Wih_f = (const float*)d_in[9];
  const float* Whh_f = (const float*)d_in[10];
  const float* bih_f = (const float*)d_in[11];
  const float* bhh_f = (const float*)d_in[12];
  const float* Wih_b = (const float*)d_in[13];
  const float* Whh_b = (const float*)d_in[14];
  const float* bih_b = (const float*)d_in[15];
  const float* bhh_b = (const float*)d_in[16];
  const float* Wps1 = (const float*)d_in[17];
  const float* bps1 = (const float*)d_in[18];
  const float* Wps2 = (const float*)d_in[19];
  const float* bps2 = (const float*)d_in[20];
  const float* Wpc1 = (const float*)d_in[21];
  const float* bpc1 = (const float*)d_in[22];
  const float* Wpc2 = (const float*)d_in[23];
  const float* bpc2 = (const float*)d_in[24];
  float* out = (float*)d_out;

  char* p = (char*)d_ws;
  auto alloc = [&](size_t bytes) -> void* {
    void* r = (void*)p;
    p += (bytes + 255) & ~(size_t)255;
    return r;
  };
  u16*   Xbf   = (u16*)alloc((size_t)XROWS * D_ * 2);
  float* G     = (float*)alloc((size_t)XROWS * G4H * 4);
  float* hW    = (float*)alloc((size_t)NSEQ * G4H * 4);
  float* hst   = (float*)alloc((size_t)NSEQ * H_ * 4);
  float* cst   = (float*)alloc((size_t)NSEQ * H_ * 4);
  u16*   hbf   = (u16*)alloc((size_t)NSEQ * H_ * 2);
  float* sf    = (float*)alloc((size_t)NSEQ * 1024 * 4);
  float* attn  = (float*)alloc((size_t)NSEQ * S_ * 4);
  float* CAT   = (float*)alloc((size_t)528 * 2048 * 4);   // rows 0..511 s_cat, 512..527 t_cat
  float* tn    = (float*)alloc(64);
  u16* Wihf_b = (u16*)alloc((size_t)G4H * D_ * 2);
  u16* Whhf_b = (u16*)alloc((size_t)G4H * H_ * 2);
  u16* Wihb_b = (u16*)alloc((size_t)G4H * D_ * 2);
  u16* Whhb_b = (u16*)alloc((size_t)G4H * H_ * 2);
  u16* W1sh = (u16*)alloc((size_t)D_ * D_ * 2); u16* W1sl = (u16*)alloc((size_t)D_ * D_ * 2);
  u16* W2sh = (u16*)alloc((size_t)D_ * D_ * 2); u16* W2sl = (u16*)alloc((size_t)D_ * D_ * 2);
  u16* W1ch = (u16*)alloc((size_t)D_ * D_ * 2); u16* W1cl = (u16*)alloc((size_t)D_ * D_ * 2);
  u16* W2ch = (u16*)alloc((size_t)D_ * D_ * 2); u16* W2cl = (u16*)alloc((size_t)D_ * D_ * 2);
  u16* SEh = (u16*)alloc((size_t)528 * D_ * 2); u16* SEl = (u16*)alloc((size_t)528 * D_ * 2);
  float* T1 = (float*)alloc((size_t)528 * D_ * 4);
  u16* T1h = (u16*)alloc((size_t)528 * D_ * 2); u16* T1l = (u16*)alloc((size_t)528 * D_ * 2);

  size_t need = (size_t)(p - (char*)d_ws);
  if (need > ws_size) {
    fprintf(stderr, "kernel_launch: ws too small, need %zu have %zu\n", need, ws_size);
    return;
  }

  auto cast = [&](const float* src, u16* dst, int n) {
    cast_kernel<<<(n + 255) / 256, 256, 0, stream>>>(src, dst, n);
  };
  auto split = [&](const float* src, u16* hi, u16* lo, int n) {
    split_kernel<<<(n + 255) / 256, 256, 0, stream>>>(src, hi, lo, n);
  };
  auto gemm = [&](const u16* A, const u16* Bm, float* Cf, u16* Cb, const float* bias,
                  int M, int N, int Kd, int ldc, int flags) {
    dim3 g((N + 127) / 128, (M + 127) / 128);
    gemm_bt_kernel<<<g, 256, 0, stream>>>(A, Bm, Cf, Cb, bias, M, N, Kd, ldc, flags);
  };

  // weight casts
  cast(Wih_f, Wihf_b, G4H * D_);
  cast(Whh_f, Whhf_b, G4H * H_);
  cast(Wih_b, Wihb_b, G4H * D_);
  cast(Whh_b, Whhb_b, G4H * H_);
  split(Wps1, W1sh, W1sl, D_ * D_);
  split(Wps2, W2sh, W2sl, D_ * D_);
  split(Wpc1, W1ch, W1cl, D_ * D_);
  split(Wpc2, W2ch, W2cl, D_ * D_);
  split(slot_emb, SEh, SEl, NSEQ * D_);
  split(tgt, SEh + (size_t)NSEQ * D_, SEl + (size_t)NSEQ * D_, NT_ * D_);

  // gather spans -> bf16
  gather_cast_kernel<<<XROWS, 256, 0, stream>>>(hidden, span_idx, Xbf);

  (void)hipMemsetAsync(sf, 0, (size_t)NSEQ * 1024 * 4, stream);

  // ---- bi-LSTM ----
  for (int dir = 0; dir < 2; ++dir) {
    const u16* Wih_bf = dir ? Wihb_b : Wihf_b;
    const u16* Whh_bf = dir ? Whhb_b : Whhf_b;
    const float* bih = dir ? bih_b : bih_f;
    const float* bhh = dir ? bhh_b : bhh_f;
    gemm(Xbf, Wih_bf, G, nullptr, nullptr, XROWS, G4H, D_, G4H, 0);
    (void)hipMemsetAsync(hst, 0, (size_t)NSEQ * H_ * 4, stream);
    (void)hipMemsetAsync(cst, 0, (size_t)NSEQ * H_ * 4, stream);
    (void)hipMemsetAsync(hbf, 0, (size_t)NSEQ * H_ * 2, stream);
    (void)hipMemsetAsync(hW, 0, (size_t)NSEQ * G4H * 4, stream);
    for (int t = 0; t < L_; ++t) {
      if (t > 0) gemm(hbf, Whh_bf, hW, nullptr, nullptr, NSEQ, G4H, H_, G4H, 0);
      int treal = dir ? (L_ - 1 - t) : t;
      lstm_gate_kernel<<<NSEQ, 256, 0, stream>>>(G, hW, bih, bhh, span_mask,
                                                 hst, cst, hbf, sf, treal, dir ? H_ : 0);
    }
  }

  // ---- outputs: slot_feats, attention, context ----
  copy_sf_kernel<<<NSEQ, 256, 0, stream>>>(sf, out);
  attn_kernel<<<NSEQ, 256, 0, stream>>>(sf, hidden, span_start, span_end, length, attn);
  context_kernel<<<NSEQ, 256, 0, stream>>>(attn, hidden, out);

  // ---- MLPs (bf16x3 for near-f32 accuracy), s and t batched: M = 528 ----
  const int M = 528;
  // ps branch -> CAT cols [0,1024)
  gemm(SEh, W1sh, T1, nullptr, nullptr, M, D_, D_, D_, 0);
  gemm(SEh, W1sl, T1, nullptr, nullptr, M, D_, D_, D_, 4);
  gemm(SEl, W1sh, T1, nullptr, bps1,    M, D_, D_, D_, 4 | 1);
  split(T1, T1h, T1l, M * D_);
  gemm(T1h, W2sh, CAT, nullptr, nullptr, M, D_, D_, 2048, 0);
  gemm(T1h, W2sl, CAT, nullptr, nullptr, M, D_, D_, 2048, 4);
  gemm(T1l, W2sh, CAT, nullptr, bps2,    M, D_, D_, 2048, 4);
  // pc branch -> CAT cols [1024,2048)
  gemm(SEh, W1ch, T1, nullptr, nullptr, M, D_, D_, D_, 0);
  gemm(SEh, W1cl, T1, nullptr, nullptr, M, D_, D_, D_, 4);
  gemm(SEl, W1ch, T1, nullptr, bpc1,    M, D_, D_, D_, 4 | 1);
  split(T1, T1h, T1l, M * D_);
  gemm(T1h, W2ch, CAT + 1024, nullptr, nullptr, M, D_, D_, 2048, 0);
  gemm(T1h, W2cl, CAT + 1024, nullptr, nullptr, M, D_, D_, 2048, 4);
  gemm(T1l, W2ch, CAT + 1024, nullptr, bpc2,    M, D_, D_, 2048, 4);

  // ---- labels ----
  const float* t_cat = CAT + (size_t)NSEQ * 2048;
  tnorm_kernel<<<NT_, 64, 0, stream>>>(t_cat, tn);
  labels_kernel<<<NSEQ, 64, 0, stream>>>(CAT, t_cat, tn, src_ids, out);
}

// Round 3
// 1341.395 us; speedup vs baseline: 1.4213x; 1.4213x over previous
//
#include <hip/hip_runtime.h>
#include <cstdio>

#define B_ 32
#define S_ 512
#define D_ 1024
#define H_ 512
#define K_ 16
#define L_ 16
#define NT_ 16
#define NSEQ 512      // B*K
#define XROWS 8192    // NSEQ*L
#define G4H 2048      // 4*H
#define OUTC 2080

typedef unsigned short u16;
typedef __bf16 bf16x8 __attribute__((ext_vector_type(8)));
typedef float f32x4 __attribute__((ext_vector_type(4)));

__device__ inline u16 f2b(float f) {
  union { float f; unsigned u; } x; x.f = f;
  unsigned r = x.u + 0x7FFFu + ((x.u >> 16) & 1u);
  return (u16)(r >> 16);
}
__device__ inline float b2f(u16 h) {
  union { unsigned u; float f; } c; c.u = ((unsigned)h) << 16;
  return c.f;
}
__device__ inline float sigf(float x) { return 1.0f / (1.0f + expf(-x)); }
__device__ inline float wredsum(float v) {
#pragma unroll
  for (int off = 32; off > 0; off >>= 1) v += __shfl_xor(v, off);
  return v;
}

// ---------------- split f32 -> hi+lo bf16 ----------------
__global__ __launch_bounds__(256) void split_kernel(const float* __restrict__ in,
                                                    u16* __restrict__ hi,
                                                    u16* __restrict__ lo, int n) {
  int i = blockIdx.x * 256 + threadIdx.x;
  if (i >= n) return;
  float x = in[i];
  u16 h = f2b(x);
  hi[i] = h;
  lo[i] = f2b(x - b2f(h));
}

// vectorized hidden split (n multiple of 4*256)
__global__ __launch_bounds__(256) void hsplit_kernel(const float* __restrict__ in,
                                                     u16* __restrict__ hi,
                                                     u16* __restrict__ lo) {
  size_t i = ((size_t)blockIdx.x * 256 + threadIdx.x) * 4;
  float4 v = *reinterpret_cast<const float4*>(in + i);
  float a[4] = {v.x, v.y, v.z, v.w};
#pragma unroll
  for (int j = 0; j < 4; ++j) {
    u16 h = f2b(a[j]);
    hi[i + j] = h;
    lo[i + j] = f2b(a[j] - b2f(h));
  }
}

// interleave-cast LSTM weight: out[j*4+g][k] = W[g*H+j][k]
__global__ __launch_bounds__(256) void icast_kernel(const float* __restrict__ W,
                                                    u16* __restrict__ out, int Kd) {
  int rp = blockIdx.x;
  int j = rp >> 2, g = rp & 3;
  const float* src = W + ((size_t)(g * H_ + j)) * Kd;
  u16* dst = out + (size_t)rp * Kd;
  for (int k = threadIdx.x; k < Kd; k += 256) dst[k] = f2b(src[k]);
}

// combined interleaved bias
__global__ __launch_bounds__(256) void bsum_kernel(const float* __restrict__ bih,
                                                   const float* __restrict__ bhh,
                                                   float* __restrict__ bsum) {
  int rp = blockIdx.x * 256 + threadIdx.x;
  if (rp >= G4H) return;
  int j = rp >> 2, g = rp & 3;
  bsum[rp] = bih[g * H_ + j] + bhh[g * H_ + j];
}

// gather span rows -> bf16
__global__ __launch_bounds__(256) void gather_cast_kernel(const float* __restrict__ hidden,
                                                          const int* __restrict__ span_idx,
                                                          u16* __restrict__ Xbf) {
  int row = blockIdx.x;          // n*L + t
  int n = row >> 4;
  int b = n >> 4;
  int s = span_idx[row];
  const float* src = hidden + ((size_t)b * S_ + s) * D_;
  u16* dst = Xbf + (size_t)row * D_;
  for (int d = threadIdx.x; d < D_; d += 256) dst[d] = f2b(src[d]);
}

// ---------------- big GEMM: C(MxN) = A(MxK) * B(NxK)^T, f32 out ----------------
__global__ __launch_bounds__(256) void gemm_bt_kernel(
    const u16* __restrict__ A, const u16* __restrict__ Bm,
    float* __restrict__ Cf, int M, int N, int Kd, int ldc) {
  __shared__ u16 As[128][34];
  __shared__ u16 Bs[128][34];
  const int tid = threadIdx.x;
  const int bm = blockIdx.y * 128, bn = blockIdx.x * 128;
  const int wave = tid >> 6, lane = tid & 63;
  const int wm = (wave >> 1) * 64, wn = (wave & 1) * 64;
  f32x4 acc[4][4] = {};
  const int lr = tid >> 2;
  const int lk = (tid & 3) * 8;
  const int fr = lane & 15;
  const int kg = (lane >> 4) * 8;

  for (int k0 = 0; k0 < Kd; k0 += 32) {
#pragma unroll
    for (int half = 0; half < 2; ++half) {
      int row = lr + half * 64;
      uint4 va = {0u, 0u, 0u, 0u};
      int ga = bm + row;
      if (ga < M) va = *reinterpret_cast<const uint4*>(A + (size_t)ga * Kd + k0 + lk);
      *reinterpret_cast<uint4*>(&As[row][lk]) = va;
      uint4 vb = {0u, 0u, 0u, 0u};
      int gb = bn + row;
      if (gb < N) vb = *reinterpret_cast<const uint4*>(Bm + (size_t)gb * Kd + k0 + lk);
      *reinterpret_cast<uint4*>(&Bs[row][lk]) = vb;
    }
    __syncthreads();
    bf16x8 af[4], bfr[4];
#pragma unroll
    for (int m = 0; m < 4; ++m)
      af[m] = *reinterpret_cast<const bf16x8*>(&As[wm + m * 16 + fr][kg]);
#pragma unroll
    for (int n = 0; n < 4; ++n)
      bfr[n] = *reinterpret_cast<const bf16x8*>(&Bs[wn + n * 16 + fr][kg]);
#pragma unroll
    for (int m = 0; m < 4; ++m)
#pragma unroll
      for (int n = 0; n < 4; ++n)
        acc[m][n] = __builtin_amdgcn_mfma_f32_16x16x32_bf16(af[m], bfr[n], acc[m][n], 0, 0, 0);
    __syncthreads();
  }
  const int ci = lane & 15;
  const int r0 = (lane >> 4) * 4;
#pragma unroll
  for (int m = 0; m < 4; ++m)
#pragma unroll
    for (int n = 0; n < 4; ++n) {
      int col = bn + wn + n * 16 + ci;
#pragma unroll
      for (int r = 0; r < 4; ++r) {
        int row = bm + wm + m * 16 + r0 + r;
        if (row < M && col < N) Cf[(size_t)row * ldc + col] = acc[m][n][r];
      }
    }
}

// ---------------- fused recurrent GEMM + LSTM gate step ----------------
// hW-tile = hbf_in(512xH) * Whh_i(2048xH)^T ; epilogue: + G + bsum, quad-shuffle
// gates, state update. Interleaved cols: c = j*4+g.
__global__ __launch_bounds__(256) void lstm_step_kernel(
    const u16* __restrict__ hbf_in, const u16* __restrict__ Whh_i,
    const float* __restrict__ G, const float* __restrict__ bsum,
    const float* __restrict__ mask,
    float* __restrict__ hst, float* __restrict__ cst,
    u16* __restrict__ hbf_out, float* __restrict__ sf,
    int treal, int coloff, int first) {
  __shared__ u16 As[64][34];
  __shared__ u16 Bs[64][34];
  const int tid = threadIdx.x;
  const int bm = blockIdx.y * 64, bn = blockIdx.x * 64;
  const int wave = tid >> 6, lane = tid & 63;
  const int wm = (wave >> 1) * 32, wn = (wave & 1) * 32;
  f32x4 acc[2][2] = {};
  const int lr = tid >> 2;
  const int lk = (tid & 3) * 8;
  const int fr = lane & 15;
  const int kg = (lane >> 4) * 8;

  if (!first) {
    for (int k0 = 0; k0 < H_; k0 += 32) {
      *reinterpret_cast<uint4*>(&As[lr][lk]) =
          *reinterpret_cast<const uint4*>(hbf_in + (size_t)(bm + lr) * H_ + k0 + lk);
      *reinterpret_cast<uint4*>(&Bs[lr][lk]) =
          *reinterpret_cast<const uint4*>(Whh_i + (size_t)(bn + lr) * H_ + k0 + lk);
      __syncthreads();
      bf16x8 af[2], bfr[2];
#pragma unroll
      for (int m = 0; m < 2; ++m)
        af[m] = *reinterpret_cast<const bf16x8*>(&As[wm + m * 16 + fr][kg]);
#pragma unroll
      for (int n = 0; n < 2; ++n)
        bfr[n] = *reinterpret_cast<const bf16x8*>(&Bs[wn + n * 16 + fr][kg]);
#pragma unroll
      for (int m = 0; m < 2; ++m)
#pragma unroll
        for (int n = 0; n < 2; ++n)
          acc[m][n] = __builtin_amdgcn_mfma_f32_16x16x32_bf16(af[m], bfr[n], acc[m][n], 0, 0, 0);
      __syncthreads();
    }
  }

  const int ci = lane & 15;
  const int r0 = (lane >> 4) * 4;
  const int q = lane & 3;
#pragma unroll
  for (int m = 0; m < 2; ++m)
#pragma unroll
    for (int n = 0; n < 2; ++n) {
      int c = bn + wn + n * 16 + ci;
      int rowbase = bm + wm + m * 16 + r0;
      float val[4];
#pragma unroll
      for (int r = 0; r < 4; ++r)
        val[r] = acc[m][n][r] + G[((size_t)(rowbase + r) * 16 + treal) * G4H + c] + bsum[c];
      // quad butterfly: gather 4 gate values per (row, j)
      float x1[4], x2[4], x3[4];
#pragma unroll
      for (int r = 0; r < 4; ++r) {
        x1[r] = __shfl_xor(val[r], 1);
        x2[r] = __shfl_xor(val[r], 2);
        x3[r] = __shfl_xor(x1[r], 2);
      }
      if (q == 0) {
        int j = c >> 2;
#pragma unroll
        for (int r = 0; r < 4; ++r) {
          int nrow = rowbase + r;
          float gi = val[r], gf = x1[r], gg = x2[r], go = x3[r];
          float mv = mask[nrow * L_ + treal];
          size_t sidx = (size_t)nrow * H_ + j;
          float co = first ? 0.f : cst[sidx];
          float ho = first ? 0.f : hst[sidx];
          float cn = sigf(gf) * co + sigf(gi) * tanhf(gg);
          float hn = sigf(go) * tanhf(cn);
          float hnew = mv * hn + (1.f - mv) * ho;
          float cnew = mv * cn + (1.f - mv) * co;
          hst[sidx] = hnew;
          cst[sidx] = cnew;
          hbf_out[sidx] = f2b(hnew);
          size_t fidx = (size_t)nrow * 1024 + coloff + j;
          float contrib = hnew * mv;
          if (first) sf[fidx] = contrib;
          else sf[fidx] += contrib;
        }
      }
    }
}

// ---------------- slot_feats: out cols [0,1024) + hi/lo split ----------------
__global__ __launch_bounds__(256) void copy_sf_split_kernel(const float* __restrict__ sf,
                                                            float* __restrict__ out,
                                                            u16* __restrict__ sfh,
                                                            u16* __restrict__ sfl) {
  int bk = blockIdx.x;
  for (int d = threadIdx.x; d < 1024; d += 256) {
    size_t i = (size_t)bk * 1024 + d;
    float v = sf[i];
    out[(size_t)bk * OUTC + d] = v;
    u16 h = f2b(v);
    sfh[i] = h;
    sfl[i] = f2b(v - b2f(h));
  }
}

// ---------------- attn = sf_b(16x1024) . hidden_b(512x1024)^T, masked, split ----------------
__global__ __launch_bounds__(256) void attn_mfma_kernel(
    const u16* __restrict__ sfh, const u16* __restrict__ sfl,
    const u16* __restrict__ Hh, const u16* __restrict__ Hl,
    const int* __restrict__ sstart, const int* __restrict__ send,
    const int* __restrict__ len,
    u16* __restrict__ attn_h, u16* __restrict__ attn_l) {
  __shared__ u16 Bh[128][34];
  __shared__ u16 Bl[128][34];
  const int b = blockIdx.x;
  const int s0 = blockIdx.y * 128;
  const int tid = threadIdx.x;
  const int wave = tid >> 6, lane = tid & 63;
  const int fr = lane & 15;
  const int kg = (lane >> 4) * 8;
  f32x4 acc[2] = {};
  const int lr = tid >> 2;
  const int lk = (tid & 3) * 8;

  for (int k0 = 0; k0 < D_; k0 += 32) {
#pragma unroll
    for (int half = 0; half < 2; ++half) {
      int srow = half * 64 + lr;
      size_t goff = ((size_t)b * S_ + s0 + srow) * D_ + k0 + lk;
      *reinterpret_cast<uint4*>(&Bh[srow][lk]) = *reinterpret_cast<const uint4*>(Hh + goff);
      *reinterpret_cast<uint4*>(&Bl[srow][lk]) = *reinterpret_cast<const uint4*>(Hl + goff);
    }
    __syncthreads();
    size_t aoff = ((size_t)b * 16 + fr) * D_ + k0 + kg;
    bf16x8 ah = *reinterpret_cast<const bf16x8*>(sfh + aoff);
    bf16x8 al = *reinterpret_cast<const bf16x8*>(sfl + aoff);
#pragma unroll
    for (int nt = 0; nt < 2; ++nt) {
      bf16x8 bh = *reinterpret_cast<const bf16x8*>(&Bh[wave * 32 + nt * 16 + fr][kg]);
      bf16x8 bl = *reinterpret_cast<const bf16x8*>(&Bl[wave * 32 + nt * 16 + fr][kg]);
      acc[nt] = __builtin_amdgcn_mfma_f32_16x16x32_bf16(ah, bh, acc[nt], 0, 0, 0);
      acc[nt] = __builtin_amdgcn_mfma_f32_16x16x32_bf16(ah, bl, acc[nt], 0, 0, 0);
      acc[nt] = __builtin_amdgcn_mfma_f32_16x16x32_bf16(al, bh, acc[nt], 0, 0, 0);
    }
    __syncthreads();
  }
  const int ln = len[b];
#pragma unroll
  for (int nt = 0; nt < 2; ++nt) {
    int s = s0 + wave * 32 + nt * 16 + (lane & 15);
#pragma unroll
    for (int r = 0; r < 4; ++r) {
      int krow = (lane >> 4) * 4 + r;
      int bk = b * 16 + krow;
      int st = sstart[bk], en = send[bk];
      bool cm = (s < st) || ((s > en) && (s < ln));
      float v = cm ? acc[nt][r] : 0.f;
      u16 h = f2b(v);
      size_t idx = (size_t)bk * S_ + s;
      attn_h[idx] = h;
      attn_l[idx] = f2b(v - b2f(h));
    }
  }
}

// ---------------- context = attn_b(16x512) . hidden_b(512x1024) -> out[.,1024+d] ----------------
__global__ __launch_bounds__(256) void ctx_mfma_kernel(
    const u16* __restrict__ attn_h, const u16* __restrict__ attn_l,
    const u16* __restrict__ Hh, const u16* __restrict__ Hl,
    float* __restrict__ out) {
  __shared__ u16 Th[128][34];   // [d][s] transposed tile
  __shared__ u16 Tl[128][34];
  const int b = blockIdx.x;
  const int d0 = blockIdx.y * 128;
  const int tid = threadIdx.x;
  const int wave = tid >> 6, lane = tid & 63;
  const int fr = lane & 15;
  const int kg = (lane >> 4) * 8;
  f32x4 acc[2] = {};

  for (int k0 = 0; k0 < S_; k0 += 32) {
    // stage 32 s-rows x 128 d, transposed
#pragma unroll
    for (int pass = 0; pass < 2; ++pass) {
      int idx = pass * 256 + tid;
      int srow = idx >> 4;
      int dch = (idx & 15) * 8;
      size_t goff = ((size_t)b * S_ + k0 + srow) * D_ + d0 + dch;
      uint4 vh = *reinterpret_cast<const uint4*>(Hh + goff);
      uint4 vl = *reinterpret_cast<const uint4*>(Hl + goff);
      const u16* ph = reinterpret_cast<const u16*>(&vh);
      const u16* pl = reinterpret_cast<const u16*>(&vl);
#pragma unroll
      for (int i = 0; i < 8; ++i) {
        Th[dch + i][srow] = ph[i];
        Tl[dch + i][srow] = pl[i];
      }
    }
    __syncthreads();
    size_t aoff = ((size_t)b * 16 + fr) * S_ + k0 + kg;
    bf16x8 ah = *reinterpret_cast<const bf16x8*>(attn_h + aoff);
    bf16x8 al = *reinterpret_cast<const bf16x8*>(attn_l + aoff);
#pragma unroll
    for (int nt = 0; nt < 2; ++nt) {
      bf16x8 bh = *reinterpret_cast<const bf16x8*>(&Th[wave * 32 + nt * 16 + fr][kg]);
      bf16x8 bl = *reinterpret_cast<const bf16x8*>(&Tl[wave * 32 + nt * 16 + fr][kg]);
      acc[nt] = __builtin_amdgcn_mfma_f32_16x16x32_bf16(ah, bh, acc[nt], 0, 0, 0);
      acc[nt] = __builtin_amdgcn_mfma_f32_16x16x32_bf16(ah, bl, acc[nt], 0, 0, 0);
      acc[nt] = __builtin_amdgcn_mfma_f32_16x16x32_bf16(al, bh, acc[nt], 0, 0, 0);
    }
    __syncthreads();
  }
#pragma unroll
  for (int nt = 0; nt < 2; ++nt) {
    int d = d0 + wave * 32 + nt * 16 + (lane & 15);
#pragma unroll
    for (int r = 0; r < 4; ++r) {
      int krow = (lane >> 4) * 4 + r;
      out[((size_t)b * 16 + krow) * OUTC + 1024 + d] = acc[nt][r];
    }
  }
}

// ---------------- 3-term split GEMM: C = Ah.Bh^T + Ah.Bl^T + Al.Bh^T (+bias)(tanh) ----------------
// flags: 1 = tanh, 2 = split bf16 out (Oh/Ol), else f32 Cf
__global__ __launch_bounds__(256) void gemm3_kernel(
    const u16* __restrict__ Ah, const u16* __restrict__ Al,
    const u16* __restrict__ Bh, const u16* __restrict__ Bl,
    float* __restrict__ Cf, u16* __restrict__ Oh, u16* __restrict__ Ol,
    const float* __restrict__ bias,
    int M, int N, int Kd, int ldc, int flags) {
  __shared__ u16 Ash[128][34];
  __shared__ u16 Asl[128][34];
  __shared__ u16 Bsh[128][34];
  __shared__ u16 Bsl[128][34];
  const int tid = threadIdx.x;
  const int bm = blockIdx.y * 128, bn = blockIdx.x * 128;
  const int wave = tid >> 6, lane = tid & 63;
  const int wm = (wave >> 1) * 64, wn = (wave & 1) * 64;
  f32x4 acc[4][4] = {};
  const int lr = tid >> 2;
  const int lk = (tid & 3) * 8;
  const int fr = lane & 15;
  const int kg = (lane >> 4) * 8;

  for (int k0 = 0; k0 < Kd; k0 += 32) {
#pragma unroll
    for (int half = 0; half < 2; ++half) {
      int row = lr + half * 64;
      uint4 vah = {0, 0, 0, 0}, val_ = {0, 0, 0, 0};
      int ga = bm + row;
      if (ga < M) {
        vah = *reinterpret_cast<const uint4*>(Ah + (size_t)ga * Kd + k0 + lk);
        val_ = *reinterpret_cast<const uint4*>(Al + (size_t)ga * Kd + k0 + lk);
      }
      *reinterpret_cast<uint4*>(&Ash[row][lk]) = vah;
      *reinterpret_cast<uint4*>(&Asl[row][lk]) = val_;
      uint4 vbh = {0, 0, 0, 0}, vbl = {0, 0, 0, 0};
      int gb = bn + row;
      if (gb < N) {
        vbh = *reinterpret_cast<const uint4*>(Bh + (size_t)gb * Kd + k0 + lk);
        vbl = *reinterpret_cast<const uint4*>(Bl + (size_t)gb * Kd + k0 + lk);
      }
      *reinterpret_cast<uint4*>(&Bsh[row][lk]) = vbh;
      *reinterpret_cast<uint4*>(&Bsl[row][lk]) = vbl;
    }
    __syncthreads();
    bf16x8 afh[4], afl[4], bfh[4], bfl[4];
#pragma unroll
    for (int m = 0; m < 4; ++m) {
      afh[m] = *reinterpret_cast<const bf16x8*>(&Ash[wm + m * 16 + fr][kg]);
      afl[m] = *reinterpret_cast<const bf16x8*>(&Asl[wm + m * 16 + fr][kg]);
    }
#pragma unroll
    for (int n = 0; n < 4; ++n) {
      bfh[n] = *reinterpret_cast<const bf16x8*>(&Bsh[wn + n * 16 + fr][kg]);
      bfl[n] = *reinterpret_cast<const bf16x8*>(&Bsl[wn + n * 16 + fr][kg]);
    }
#pragma unroll
    for (int m = 0; m < 4; ++m)
#pragma unroll
      for (int n = 0; n < 4; ++n) {
        acc[m][n] = __builtin_amdgcn_mfma_f32_16x16x32_bf16(afh[m], bfh[n], acc[m][n], 0, 0, 0);
        acc[m][n] = __builtin_amdgcn_mfma_f32_16x16x32_bf16(afh[m], bfl[n], acc[m][n], 0, 0, 0);
        acc[m][n] = __builtin_amdgcn_mfma_f32_16x16x32_bf16(afl[m], bfh[n], acc[m][n], 0, 0, 0);
      }
    __syncthreads();
  }
  const int ci = lane & 15;
  const int r0 = (lane >> 4) * 4;
#pragma unroll
  for (int m = 0; m < 4; ++m)
#pragma unroll
    for (int n = 0; n < 4; ++n) {
      int col = bn + wn + n * 16 + ci;
#pragma unroll
      for (int r = 0; r < 4; ++r) {
        int row = bm + wm + m * 16 + r0 + r;
        if (row < M && col < N) {
          size_t idx = (size_t)row * ldc + col;
          float v = acc[m][n][r];
          if (bias) v += bias[col];
          if (flags & 1) v = tanhf(v);
          if (flags & 2) {
            u16 h = f2b(v);
            Oh[idx] = h;
            Ol[idx] = f2b(v - b2f(h));
          } else {
            Cf[idx] = v;
          }
        }
      }
    }
}

// ---------------- labels (tnorm inlined): out cols [2048,2080) ----------------
__global__ __launch_bounds__(64) void labels_kernel(
    const float* __restrict__ s_cat, const float* __restrict__ t_cat,
    const int* __restrict__ src_ids, float* __restrict__ out) {
  int bk = blockIdx.x, lane = threadIdx.x;
  const float* srow = s_cat + (size_t)bk * 2048;
  float np = 0.f;
  float dots[16], tsq[16];
#pragma unroll
  for (int t = 0; t < 16; ++t) { dots[t] = 0.f; tsq[t] = 0.f; }
  for (int j = lane; j < 2048; j += 64) {
    float sv = srow[j];
    np += sv * sv;
#pragma unroll
    for (int t = 0; t < 16; ++t) {
      float tv = t_cat[t * 2048 + j];
      dots[t] += sv * tv;
      tsq[t] += tv * tv;
    }
  }
  np = wredsum(np);
#pragma unroll
  for (int t = 0; t < 16; ++t) { dots[t] = wredsum(dots[t]); tsq[t] = wredsum(tsq[t]); }
  float sn = fmaxf(sqrtf(np), 1e-8f);
  float ssum = 0.f;
  float sims[16];
#pragma unroll
  for (int t = 0; t < 16; ++t) {
    float tn = fmaxf(sqrtf(tsq[t]), 1e-8f);
    sims[t] = dots[t] / (sn * tn);
    ssum += sims[t];
  }
  float scale = 0.9f / ssum;
  if (lane < 16) {
    out[(size_t)bk * OUTC + 2064 + lane] = sims[lane] * scale;
  } else if (lane < 32) {
    int t2 = lane - 16;
    out[(size_t)bk * OUTC + 2048 + t2] = (src_ids[bk] == t2) ? 0.1f : 0.f;
  }
}

// =======================================================================
extern "C" void kernel_launch(void* const* d_in, const int* in_sizes, int n_in,
                              void* d_out, int out_size, void* d_ws, size_t ws_size,
                              hipStream_t stream) {
  const float* hidden    = (const float*)d_in[0];
  const int*   span_idx  = (const int*)d_in[1];
  const float* span_mask = (const float*)d_in[2];
  const int*   span_start= (const int*)d_in[3];
  const int*   span_end  = (const int*)d_in[4];
  const int*   length    = (const int*)d_in[5];
  const float* slot_emb  = (const float*)d_in[6];
  const float* tgt       = (const float*)d_in[7];
  const int*   src_ids   = (const int*)d_in[8];
  const float* Wih_f = (const float*)d_in[9];
  const float* Whh_f = (const float*)d_in[10];
  const float* bih_f = (const float*)d_in[11];
  const float* bhh_f = (const float*)d_in[12];
  const float* Wih_b = (const float*)d_in[13];
  const float* Whh_b = (const float*)d_in[14];
  const float* bih_b = (const float*)d_in[15];
  const float* bhh_b = (const float*)d_in[16];
  const float* Wps1 = (const float*)d_in[17];
  const float* bps1 = (const float*)d_in[18];
  const float* Wps2 = (const float*)d_in[19];
  const float* bps2 = (const float*)d_in[20];
  const float* Wpc1 = (const float*)d_in[21];
  const float* bpc1 = (const float*)d_in[22];
  const float* Wpc2 = (const float*)d_in[23];
  const float* bpc2 = (const float*)d_in[24];
  float* out = (float*)d_out;

  char* p = (char*)d_ws;
  auto alloc = [&](size_t bytes) -> void* {
    void* r = (void*)p;
    p += (bytes + 255) & ~(size_t)255;
    return r;
  };
  u16*   Xbf   = (u16*)alloc((size_t)XROWS * D_ * 2);
  float* G     = (float*)alloc((size_t)XROWS * G4H * 4);
  float* hst   = (float*)alloc((size_t)NSEQ * H_ * 4);
  float* cst   = (float*)alloc((size_t)NSEQ * H_ * 4);
  u16*   hbfA  = (u16*)alloc((size_t)NSEQ * H_ * 2);
  u16*   hbfB  = (u16*)alloc((size_t)NSEQ * H_ * 2);
  float* sf    = (float*)alloc((size_t)NSEQ * 1024 * 4);
  u16*   sfh   = (u16*)alloc((size_t)NSEQ * 1024 * 2);
  u16*   sfl   = (u16*)alloc((size_t)NSEQ * 1024 * 2);
  u16*   attn_h= (u16*)alloc((size_t)NSEQ * S_ * 2);
  u16*   attn_l= (u16*)alloc((size_t)NSEQ * S_ * 2);
  float* CAT   = (float*)alloc((size_t)528 * 2048 * 4);
  u16* Wihf_i = (u16*)alloc((size_t)G4H * D_ * 2);
  u16* Whhf_i = (u16*)alloc((size_t)G4H * H_ * 2);
  u16* Wihb_i = (u16*)alloc((size_t)G4H * D_ * 2);
  u16* Whhb_i = (u16*)alloc((size_t)G4H * H_ * 2);
  float* bsumf = (float*)alloc(G4H * 4);
  float* bsumb = (float*)alloc(G4H * 4);
  u16* W1sh = (u16*)alloc((size_t)D_ * D_ * 2); u16* W1sl = (u16*)alloc((size_t)D_ * D_ * 2);
  u16* W2sh = (u16*)alloc((size_t)D_ * D_ * 2); u16* W2sl = (u16*)alloc((size_t)D_ * D_ * 2);
  u16* W1ch = (u16*)alloc((size_t)D_ * D_ * 2); u16* W1cl = (u16*)alloc((size_t)D_ * D_ * 2);
  u16* W2ch = (u16*)alloc((size_t)D_ * D_ * 2); u16* W2cl = (u16*)alloc((size_t)D_ * D_ * 2);
  u16* SEh = (u16*)alloc((size_t)528 * D_ * 2); u16* SEl = (u16*)alloc((size_t)528 * D_ * 2);
  u16* T1h = (u16*)alloc((size_t)528 * D_ * 2); u16* T1l = (u16*)alloc((size_t)528 * D_ * 2);
  // hidden hi/lo splits alias the dead G buffer (G: 64 MB == 2 x 32 MB)
  u16* Hh = (u16*)G;
  u16* Hl = Hh + (size_t)B_ * S_ * D_;

  size_t need = (size_t)(p - (char*)d_ws);
  if (need > ws_size) {
    fprintf(stderr, "kernel_launch: ws too small, need %zu have %zu\n", need, ws_size);
    return;
  }

  auto split = [&](const float* src, u16* hi, u16* lo, int n) {
    split_kernel<<<(n + 255) / 256, 256, 0, stream>>>(src, hi, lo, n);
  };

  // weight prep
  icast_kernel<<<G4H, 256, 0, stream>>>(Wih_f, Wihf_i, D_);
  icast_kernel<<<G4H, 256, 0, stream>>>(Whh_f, Whhf_i, H_);
  icast_kernel<<<G4H, 256, 0, stream>>>(Wih_b, Wihb_i, D_);
  icast_kernel<<<G4H, 256, 0, stream>>>(Whh_b, Whhb_i, H_);
  bsum_kernel<<<8, 256, 0, stream>>>(bih_f, bhh_f, bsumf);
  bsum_kernel<<<8, 256, 0, stream>>>(bih_b, bhh_b, bsumb);
  split(Wps1, W1sh, W1sl, D_ * D_);
  split(Wps2, W2sh, W2sl, D_ * D_);
  split(Wpc1, W1ch, W1cl, D_ * D_);
  split(Wpc2, W2ch, W2cl, D_ * D_);
  split(slot_emb, SEh, SEl, NSEQ * D_);
  split(tgt, SEh + (size_t)NSEQ * D_, SEl + (size_t)NSEQ * D_, NT_ * D_);

  gather_cast_kernel<<<XROWS, 256, 0, stream>>>(hidden, span_idx, Xbf);

  // ---- bi-LSTM: big input GEMM + 16 fused steps per direction ----
  for (int dir = 0; dir < 2; ++dir) {
    const u16* Wih_i = dir ? Wihb_i : Wihf_i;
    const u16* Whh_i = dir ? Whhb_i : Whhf_i;
    const float* bsum = dir ? bsumb : bsumf;
    {
      dim3 g(G4H / 128, XROWS / 128);
      gemm_bt_kernel<<<g, 256, 0, stream>>>(Xbf, Wih_i, G, XROWS, G4H, D_, G4H);
    }
    for (int t = 0; t < L_; ++t) {
      int treal = dir ? (L_ - 1 - t) : t;
      const u16* hin = (t & 1) ? hbfA : hbfB;
      u16* hout = (t & 1) ? hbfB : hbfA;
      dim3 g(G4H / 64, NSEQ / 64);
      lstm_step_kernel<<<g, 256, 0, stream>>>(hin, Whh_i, G, bsum, span_mask,
                                              hst, cst, hout, sf,
                                              treal, dir ? H_ : 0, t == 0 ? 1 : 0);
    }
  }

  // ---- slot_feats out + splits ----
  copy_sf_split_kernel<<<NSEQ, 256, 0, stream>>>(sf, out, sfh, sfl);

  // ---- hidden hi/lo split (into G alias; G is dead now) ----
  hsplit_kernel<<<(B_ * S_ * D_) / (4 * 256), 256, 0, stream>>>(hidden, Hh, Hl);

  // ---- attention + context (3-term split MFMA) ----
  {
    dim3 g(B_, S_ / 128);
    attn_mfma_kernel<<<g, 256, 0, stream>>>(sfh, sfl, Hh, Hl,
                                            span_start, span_end, length,
                                            attn_h, attn_l);
  }
  {
    dim3 g(B_, D_ / 128);
    ctx_mfma_kernel<<<g, 256, 0, stream>>>(attn_h, attn_l, Hh, Hl, out);
  }

  // ---- MLPs: 4 fused 3-term GEMMs ----
  const int M = 528;
  auto gemm3 = [&](const u16* Ah, const u16* Al, const u16* Bh, const u16* Bl,
                   float* Cf, u16* Oh, u16* Ol, const float* bias, int ldc, int flags) {
    dim3 g(D_ / 128, (M + 127) / 128);
    gemm3_kernel<<<g, 256, 0, stream>>>(Ah, Al, Bh, Bl, Cf, Oh, Ol, bias,
                                        M, D_, D_, ldc, flags);
  };
  // ps branch
  gemm3(SEh, SEl, W1sh, W1sl, nullptr, T1h, T1l, bps1, D_, 1 | 2);
  gemm3(T1h, T1l, W2sh, W2sl, CAT, nullptr, nullptr, bps2, 2048, 0);
  // pc branch
  gemm3(SEh, SEl, W1ch, W1cl, nullptr, T1h, T1l, bpc1, D_, 1 | 2);
  gemm3(T1h, T1l, W2ch, W2cl, CAT + 1024, nullptr, nullptr, bpc2, 2048, 0);

  // ---- labels ----
  const float* t_cat = CAT + (size_t)NSEQ * 2048;
  labels_kernel<<<NSEQ, 64, 0, stream>>>(CAT, t_cat, src_ids, out);
}

// Round 4
// 776.133 us; speedup vs baseline: 2.4564x; 1.7283x over previous
//
#include <hip/hip_runtime.h>
#include <cstdio>

#define B_ 32
#define S_ 512
#define D_ 1024
#define H_ 512
#define K_ 16
#define L_ 16
#define NT_ 16
#define NSEQ 512      // B*K
#define XROWS 8192    // NSEQ*L
#define G4H 2048      // 4*H
#define OUTC 2080
#define MROWS 528     // NSEQ + NT

typedef unsigned short u16;
typedef __bf16 bf16x8 __attribute__((ext_vector_type(8)));
typedef float f32x4 __attribute__((ext_vector_type(4)));

__device__ inline u16 f2b(float f) {
  union { float f; unsigned u; } x; x.f = f;
  unsigned r = x.u + 0x7FFFu + ((x.u >> 16) & 1u);
  return (u16)(r >> 16);
}
__device__ inline float b2f(u16 h) {
  union { unsigned u; float f; } c; c.u = ((unsigned)h) << 16;
  return c.f;
}
__device__ inline float sigf(float x) { return 1.0f / (1.0f + expf(-x)); }
__device__ inline float wredsum(float v) {
#pragma unroll
  for (int off = 32; off > 0; off >>= 1) v += __shfl_xor(v, off);
  return v;
}

// ---------------- split f32 -> hi+lo bf16 ----------------
__global__ __launch_bounds__(256) void split_kernel(const float* __restrict__ in,
                                                    u16* __restrict__ hi,
                                                    u16* __restrict__ lo, int n) {
  int i = blockIdx.x * 256 + threadIdx.x;
  if (i >= n) return;
  float x = in[i];
  u16 h = f2b(x);
  hi[i] = h;
  lo[i] = f2b(x - b2f(h));
}

// vectorized hidden split (n multiple of 4*256)
__global__ __launch_bounds__(256) void hsplit_kernel(const float* __restrict__ in,
                                                     u16* __restrict__ hi,
                                                     u16* __restrict__ lo) {
  size_t i = ((size_t)blockIdx.x * 256 + threadIdx.x) * 4;
  float4 v = *reinterpret_cast<const float4*>(in + i);
  float a[4] = {v.x, v.y, v.z, v.w};
#pragma unroll
  for (int j = 0; j < 4; ++j) {
    u16 h = f2b(a[j]);
    hi[i + j] = h;
    lo[i + j] = f2b(a[j] - b2f(h));
  }
}

// interleave-cast LSTM weight: out[j*4+g][k] = W[g*H+j][k]
__global__ __launch_bounds__(256) void icast_kernel(const float* __restrict__ W,
                                                    u16* __restrict__ out, int Kd) {
  int rp = blockIdx.x;
  int j = rp >> 2, g = rp & 3;
  const float* src = W + ((size_t)(g * H_ + j)) * Kd;
  u16* dst = out + (size_t)rp * Kd;
  for (int k = threadIdx.x; k < Kd; k += 256) dst[k] = f2b(src[k]);
}

// combined interleaved bias
__global__ __launch_bounds__(256) void bsum_kernel(const float* __restrict__ bih,
                                                   const float* __restrict__ bhh,
                                                   float* __restrict__ bsum) {
  int rp = blockIdx.x * 256 + threadIdx.x;
  if (rp >= G4H) return;
  int j = rp >> 2, g = rp & 3;
  bsum[rp] = bih[g * H_ + j] + bhh[g * H_ + j];
}

// gather span rows -> bf16
__global__ __launch_bounds__(256) void gather_cast_kernel(const float* __restrict__ hidden,
                                                          const int* __restrict__ span_idx,
                                                          u16* __restrict__ Xbf) {
  int row = blockIdx.x;          // n*L + t
  int n = row >> 4;
  int b = n >> 4;
  int s = span_idx[row];
  const float* src = hidden + ((size_t)b * S_ + s) * D_;
  u16* dst = Xbf + (size_t)row * D_;
  for (int d = threadIdx.x; d < D_; d += 256) dst[d] = f2b(src[d]);
}

// ---------------- big GEMM: C(MxN) = A(MxK) * B(NxK)^T ----------------
// Cb != nullptr -> bf16 out, else f32 Cf
__global__ __launch_bounds__(256) void gemm_bt_kernel(
    const u16* __restrict__ A, const u16* __restrict__ Bm,
    float* __restrict__ Cf, u16* __restrict__ Cb,
    int M, int N, int Kd, int ldc) {
  __shared__ u16 As[128][34];
  __shared__ u16 Bs[128][34];
  const int tid = threadIdx.x;
  const int bm = blockIdx.y * 128, bn = blockIdx.x * 128;
  const int wave = tid >> 6, lane = tid & 63;
  const int wm = (wave >> 1) * 64, wn = (wave & 1) * 64;
  f32x4 acc[4][4] = {};
  const int lr = tid >> 2;
  const int lk = (tid & 3) * 8;
  const int fr = lane & 15;
  const int kg = (lane >> 4) * 8;

  for (int k0 = 0; k0 < Kd; k0 += 32) {
#pragma unroll
    for (int half = 0; half < 2; ++half) {
      int row = lr + half * 64;
      uint4 va = {0u, 0u, 0u, 0u};
      int ga = bm + row;
      if (ga < M) va = *reinterpret_cast<const uint4*>(A + (size_t)ga * Kd + k0 + lk);
      *reinterpret_cast<uint4*>(&As[row][lk]) = va;
      uint4 vb = {0u, 0u, 0u, 0u};
      int gb = bn + row;
      if (gb < N) vb = *reinterpret_cast<const uint4*>(Bm + (size_t)gb * Kd + k0 + lk);
      *reinterpret_cast<uint4*>(&Bs[row][lk]) = vb;
    }
    __syncthreads();
    bf16x8 af[4], bfr[4];
#pragma unroll
    for (int m = 0; m < 4; ++m)
      af[m] = *reinterpret_cast<const bf16x8*>(&As[wm + m * 16 + fr][kg]);
#pragma unroll
    for (int n = 0; n < 4; ++n)
      bfr[n] = *reinterpret_cast<const bf16x8*>(&Bs[wn + n * 16 + fr][kg]);
#pragma unroll
    for (int m = 0; m < 4; ++m)
#pragma unroll
      for (int n = 0; n < 4; ++n)
        acc[m][n] = __builtin_amdgcn_mfma_f32_16x16x32_bf16(af[m], bfr[n], acc[m][n], 0, 0, 0);
    __syncthreads();
  }
  const int ci = lane & 15;
  const int r0 = (lane >> 4) * 4;
#pragma unroll
  for (int m = 0; m < 4; ++m)
#pragma unroll
    for (int n = 0; n < 4; ++n) {
      int col = bn + wn + n * 16 + ci;
#pragma unroll
      for (int r = 0; r < 4; ++r) {
        int row = bm + wm + m * 16 + r0 + r;
        if (row < M && col < N) {
          size_t idx = (size_t)row * ldc + col;
          if (Cb) Cb[idx] = f2b(acc[m][n][r]);
          else Cf[idx] = acc[m][n][r];
        }
      }
    }
}

// ---------------- fused recurrent GEMM + LSTM gate step (both dirs via z) ------
// z = dir. G2 bf16 [XROWS][4096]: cols [dir*2048 + j*4+g].
__global__ __launch_bounds__(256) void lstm_step_kernel(
    const u16* __restrict__ hbf_in,   // [2][NSEQ][H]
    const u16* __restrict__ Whhf, const u16* __restrict__ Whhb,
    const u16* __restrict__ G2,
    const float* __restrict__ bsumf, const float* __restrict__ bsumb,
    const float* __restrict__ mask,
    float* __restrict__ hst, float* __restrict__ cst,   // [2][NSEQ][H]
    u16* __restrict__ hbf_out,        // [2][NSEQ][H]
    float* __restrict__ sf,           // [NSEQ][1024]
    int t, int first) {
  __shared__ u16 As[64][34];
  __shared__ u16 Bs[64][34];
  const int tid = threadIdx.x;
  const int bz = blockIdx.z;
  const int treal = bz ? (L_ - 1 - t) : t;
  const u16* Whh = bz ? Whhb : Whhf;
  const float* bsum = bz ? bsumb : bsumf;
  const size_t sofs = (size_t)bz * NSEQ * H_;
  const int bm = blockIdx.y * 64, bn = blockIdx.x * 64;
  const int wave = tid >> 6, lane = tid & 63;
  const int wm = (wave >> 1) * 32, wn = (wave & 1) * 32;
  f32x4 acc[2][2] = {};
  const int lr = tid >> 2;
  const int lk = (tid & 3) * 8;
  const int fr = lane & 15;
  const int kg = (lane >> 4) * 8;

  if (!first) {
    for (int k0 = 0; k0 < H_; k0 += 32) {
      *reinterpret_cast<uint4*>(&As[lr][lk]) =
          *reinterpret_cast<const uint4*>(hbf_in + sofs + (size_t)(bm + lr) * H_ + k0 + lk);
      *reinterpret_cast<uint4*>(&Bs[lr][lk]) =
          *reinterpret_cast<const uint4*>(Whh + (size_t)(bn + lr) * H_ + k0 + lk);
      __syncthreads();
      bf16x8 af[2], bfr[2];
#pragma unroll
      for (int m = 0; m < 2; ++m)
        af[m] = *reinterpret_cast<const bf16x8*>(&As[wm + m * 16 + fr][kg]);
#pragma unroll
      for (int n = 0; n < 2; ++n)
        bfr[n] = *reinterpret_cast<const bf16x8*>(&Bs[wn + n * 16 + fr][kg]);
#pragma unroll
      for (int m = 0; m < 2; ++m)
#pragma unroll
        for (int n = 0; n < 2; ++n)
          acc[m][n] = __builtin_amdgcn_mfma_f32_16x16x32_bf16(af[m], bfr[n], acc[m][n], 0, 0, 0);
      __syncthreads();
    }
  }

  const int ci = lane & 15;
  const int r0 = (lane >> 4) * 4;
  const int q = lane & 3;
#pragma unroll
  for (int m = 0; m < 2; ++m)
#pragma unroll
    for (int n = 0; n < 2; ++n) {
      int c = bn + wn + n * 16 + ci;
      int rowbase = bm + wm + m * 16 + r0;
      float val[4];
#pragma unroll
      for (int r = 0; r < 4; ++r) {
        int nrow = rowbase + r;
        float g2 = b2f(G2[((size_t)nrow * L_ + treal) * 4096 + (size_t)bz * 2048 + c]);
        val[r] = acc[m][n][r] + g2 + bsum[c];
      }
      float x1[4], x2[4], x3[4];
#pragma unroll
      for (int r = 0; r < 4; ++r) {
        x1[r] = __shfl_xor(val[r], 1);
        x2[r] = __shfl_xor(val[r], 2);
        x3[r] = __shfl_xor(x1[r], 2);
      }
      if (q == 0) {
        int j = c >> 2;
#pragma unroll
        for (int r = 0; r < 4; ++r) {
          int nrow = rowbase + r;
          float gi = val[r], gf = x1[r], gg = x2[r], go = x3[r];
          float mv = mask[nrow * L_ + treal];
          size_t sidx = sofs + (size_t)nrow * H_ + j;
          float co = first ? 0.f : cst[sidx];
          float ho = first ? 0.f : hst[sidx];
          float cn = sigf(gf) * co + sigf(gi) * tanhf(gg);
          float hn = sigf(go) * tanhf(cn);
          float hnew = mv * hn + (1.f - mv) * ho;
          float cnew = mv * cn + (1.f - mv) * co;
          hst[sidx] = hnew;
          cst[sidx] = cnew;
          hbf_out[sidx] = f2b(hnew);
          size_t fidx = (size_t)nrow * 1024 + bz * 512 + j;
          float contrib = hnew * mv;
          if (first) sf[fidx] = contrib;
          else sf[fidx] += contrib;
        }
      }
    }
}

// ---------------- slot_feats: out cols [0,1024) + hi/lo split ----------------
__global__ __launch_bounds__(256) void copy_sf_split_kernel(const float* __restrict__ sf,
                                                            float* __restrict__ out,
                                                            u16* __restrict__ sfh,
                                                            u16* __restrict__ sfl) {
  int bk = blockIdx.x;
  for (int d = threadIdx.x; d < 1024; d += 256) {
    size_t i = (size_t)bk * 1024 + d;
    float v = sf[i];
    out[(size_t)bk * OUTC + d] = v;
    u16 h = f2b(v);
    sfh[i] = h;
    sfl[i] = f2b(v - b2f(h));
  }
}

// ---------------- attn = sf_b(16x1024) . hidden_b(512x1024)^T, masked, split ----------------
__global__ __launch_bounds__(256) void attn_mfma_kernel(
    const u16* __restrict__ sfh, const u16* __restrict__ sfl,
    const u16* __restrict__ Hh, const u16* __restrict__ Hl,
    const int* __restrict__ sstart, const int* __restrict__ send,
    const int* __restrict__ len,
    u16* __restrict__ attn_h, u16* __restrict__ attn_l) {
  __shared__ u16 Bh[128][34];
  __shared__ u16 Bl[128][34];
  const int b = blockIdx.x;
  const int s0 = blockIdx.y * 128;
  const int tid = threadIdx.x;
  const int wave = tid >> 6, lane = tid & 63;
  const int fr = lane & 15;
  const int kg = (lane >> 4) * 8;
  f32x4 acc[2] = {};
  const int lr = tid >> 2;
  const int lk = (tid & 3) * 8;

  for (int k0 = 0; k0 < D_; k0 += 32) {
#pragma unroll
    for (int half = 0; half < 2; ++half) {
      int srow = half * 64 + lr;
      size_t goff = ((size_t)b * S_ + s0 + srow) * D_ + k0 + lk;
      *reinterpret_cast<uint4*>(&Bh[srow][lk]) = *reinterpret_cast<const uint4*>(Hh + goff);
      *reinterpret_cast<uint4*>(&Bl[srow][lk]) = *reinterpret_cast<const uint4*>(Hl + goff);
    }
    __syncthreads();
    size_t aoff = ((size_t)b * 16 + fr) * D_ + k0 + kg;
    bf16x8 ah = *reinterpret_cast<const bf16x8*>(sfh + aoff);
    bf16x8 al = *reinterpret_cast<const bf16x8*>(sfl + aoff);
#pragma unroll
    for (int nt = 0; nt < 2; ++nt) {
      bf16x8 bh = *reinterpret_cast<const bf16x8*>(&Bh[wave * 32 + nt * 16 + fr][kg]);
      bf16x8 bl = *reinterpret_cast<const bf16x8*>(&Bl[wave * 32 + nt * 16 + fr][kg]);
      acc[nt] = __builtin_amdgcn_mfma_f32_16x16x32_bf16(ah, bh, acc[nt], 0, 0, 0);
      acc[nt] = __builtin_amdgcn_mfma_f32_16x16x32_bf16(ah, bl, acc[nt], 0, 0, 0);
      acc[nt] = __builtin_amdgcn_mfma_f32_16x16x32_bf16(al, bh, acc[nt], 0, 0, 0);
    }
    __syncthreads();
  }
  const int ln = len[b];
#pragma unroll
  for (int nt = 0; nt < 2; ++nt) {
    int s = s0 + wave * 32 + nt * 16 + (lane & 15);
#pragma unroll
    for (int r = 0; r < 4; ++r) {
      int krow = (lane >> 4) * 4 + r;
      int bk = b * 16 + krow;
      int st = sstart[bk], en = send[bk];
      bool cm = (s < st) || ((s > en) && (s < ln));
      float v = cm ? acc[nt][r] : 0.f;
      u16 h = f2b(v);
      size_t idx = (size_t)bk * S_ + s;
      attn_h[idx] = h;
      attn_l[idx] = f2b(v - b2f(h));
    }
  }
}

// ---------------- context = attn_b(16x512) . hidden_b(512x1024) -> out[.,1024+d] ----------------
__global__ __launch_bounds__(256) void ctx_mfma_kernel(
    const u16* __restrict__ attn_h, const u16* __restrict__ attn_l,
    const u16* __restrict__ Hh, const u16* __restrict__ Hl,
    float* __restrict__ out) {
  __shared__ u16 Th[128][34];   // [d][s] transposed tile
  __shared__ u16 Tl[128][34];
  const int b = blockIdx.x;
  const int d0 = blockIdx.y * 128;
  const int tid = threadIdx.x;
  const int wave = tid >> 6, lane = tid & 63;
  const int fr = lane & 15;
  const int kg = (lane >> 4) * 8;
  f32x4 acc[2] = {};

  for (int k0 = 0; k0 < S_; k0 += 32) {
#pragma unroll
    for (int pass = 0; pass < 2; ++pass) {
      int idx = pass * 256 + tid;
      int srow = idx >> 4;
      int dch = (idx & 15) * 8;
      size_t goff = ((size_t)b * S_ + k0 + srow) * D_ + d0 + dch;
      uint4 vh = *reinterpret_cast<const uint4*>(Hh + goff);
      uint4 vl = *reinterpret_cast<const uint4*>(Hl + goff);
      const u16* ph = reinterpret_cast<const u16*>(&vh);
      const u16* pl = reinterpret_cast<const u16*>(&vl);
#pragma unroll
      for (int i = 0; i < 8; ++i) {
        Th[dch + i][srow] = ph[i];
        Tl[dch + i][srow] = pl[i];
      }
    }
    __syncthreads();
    size_t aoff = ((size_t)b * 16 + fr) * S_ + k0 + kg;
    bf16x8 ah = *reinterpret_cast<const bf16x8*>(attn_h + aoff);
    bf16x8 al = *reinterpret_cast<const bf16x8*>(attn_l + aoff);
#pragma unroll
    for (int nt = 0; nt < 2; ++nt) {
      bf16x8 bh = *reinterpret_cast<const bf16x8*>(&Th[wave * 32 + nt * 16 + fr][kg]);
      bf16x8 bl = *reinterpret_cast<const bf16x8*>(&Tl[wave * 32 + nt * 16 + fr][kg]);
      acc[nt] = __builtin_amdgcn_mfma_f32_16x16x32_bf16(ah, bh, acc[nt], 0, 0, 0);
      acc[nt] = __builtin_amdgcn_mfma_f32_16x16x32_bf16(ah, bl, acc[nt], 0, 0, 0);
      acc[nt] = __builtin_amdgcn_mfma_f32_16x16x32_bf16(al, bh, acc[nt], 0, 0, 0);
    }
    __syncthreads();
  }
#pragma unroll
  for (int nt = 0; nt < 2; ++nt) {
    int d = d0 + wave * 32 + nt * 16 + (lane & 15);
#pragma unroll
    for (int r = 0; r < 4; ++r) {
      int krow = (lane >> 4) * 4 + r;
      out[((size_t)b * 16 + krow) * OUTC + 1024 + d] = acc[nt][r];
    }
  }
}

// ---------------- MLP split-K GEMM: P[z] = 3-term partials over K-slice ----------------
// blockIdx.z = branch*4 + kslice. 64x64 tile. A optionally branch-strided.
__global__ __launch_bounds__(256) void mlp_gemm_kernel(
    const u16* __restrict__ Ah, const u16* __restrict__ Al, int a_br_stride,
    const u16* __restrict__ B0h, const u16* __restrict__ B0l,
    const u16* __restrict__ B1h, const u16* __restrict__ B1l,
    float* __restrict__ P, int M) {
  __shared__ u16 Ash[64][34];
  __shared__ u16 Asl[64][34];
  __shared__ u16 Bsh[64][34];
  __shared__ u16 Bsl[64][34];
  const int tid = threadIdx.x;
  const int zz = blockIdx.z;
  const int br = zz >> 2, ks = zz & 3;
  const u16* Ah_ = Ah + (size_t)br * a_br_stride;
  const u16* Al_ = Al + (size_t)br * a_br_stride;
  const u16* Bh = br ? B1h : B0h;
  const u16* Bl = br ? B1l : B0l;
  const int bm = blockIdx.y * 64, bn = blockIdx.x * 64;
  const int wave = tid >> 6, lane = tid & 63;
  const int wm = (wave >> 1) * 32, wn = (wave & 1) * 32;
  f32x4 acc[2][2] = {};
  const int lr = tid >> 2;
  const int lk = (tid & 3) * 8;
  const int fr = lane & 15;
  const int kg = (lane >> 4) * 8;

  const int kbeg = ks * 256;
  for (int k0 = kbeg; k0 < kbeg + 256; k0 += 32) {
    int ga = bm + lr;
    uint4 vah = {0, 0, 0, 0}, vall = {0, 0, 0, 0};
    if (ga < M) {
      vah = *reinterpret_cast<const uint4*>(Ah_ + (size_t)ga * D_ + k0 + lk);
      vall = *reinterpret_cast<const uint4*>(Al_ + (size_t)ga * D_ + k0 + lk);
    }
    *reinterpret_cast<uint4*>(&Ash[lr][lk]) = vah;
    *reinterpret_cast<uint4*>(&Asl[lr][lk]) = vall;
    *reinterpret_cast<uint4*>(&Bsh[lr][lk]) =
        *reinterpret_cast<const uint4*>(Bh + (size_t)(bn + lr) * D_ + k0 + lk);
    *reinterpret_cast<uint4*>(&Bsl[lr][lk]) =
        *reinterpret_cast<const uint4*>(Bl + (size_t)(bn + lr) * D_ + k0 + lk);
    __syncthreads();
    bf16x8 afh[2], afl[2], bfh[2], bfl[2];
#pragma unroll
    for (int m = 0; m < 2; ++m) {
      afh[m] = *reinterpret_cast<const bf16x8*>(&Ash[wm + m * 16 + fr][kg]);
      afl[m] = *reinterpret_cast<const bf16x8*>(&Asl[wm + m * 16 + fr][kg]);
    }
#pragma unroll
    for (int n = 0; n < 2; ++n) {
      bfh[n] = *reinterpret_cast<const bf16x8*>(&Bsh[wn + n * 16 + fr][kg]);
      bfl[n] = *reinterpret_cast<const bf16x8*>(&Bsl[wn + n * 16 + fr][kg]);
    }
#pragma unroll
    for (int m = 0; m < 2; ++m)
#pragma unroll
      for (int n = 0; n < 2; ++n) {
        acc[m][n] = __builtin_amdgcn_mfma_f32_16x16x32_bf16(afh[m], bfh[n], acc[m][n], 0, 0, 0);
        acc[m][n] = __builtin_amdgcn_mfma_f32_16x16x32_bf16(afh[m], bfl[n], acc[m][n], 0, 0, 0);
        acc[m][n] = __builtin_amdgcn_mfma_f32_16x16x32_bf16(afl[m], bfh[n], acc[m][n], 0, 0, 0);
      }
    __syncthreads();
  }
  const int ci = lane & 15;
  const int r0 = (lane >> 4) * 4;
#pragma unroll
  for (int m = 0; m < 2; ++m)
#pragma unroll
    for (int n = 0; n < 2; ++n) {
      int col = bn + wn + n * 16 + ci;
#pragma unroll
      for (int r = 0; r < 4; ++r) {
        int row = bm + wm + m * 16 + r0 + r;
        if (row < M)
          P[((size_t)zz * MROWS + row) * D_ + col] = acc[m][n][r];
      }
    }
}

// ---------------- MLP reduce: sum 4 k-slices, +bias, (tanh+split) or f32->CAT ----
__global__ __launch_bounds__(256) void mlp_reduce_kernel(
    const float* __restrict__ P,
    const float* __restrict__ bias0, const float* __restrict__ bias1,
    u16* __restrict__ Oh, u16* __restrict__ Ol,   // mode 0: [2][MROWS][D]
    float* __restrict__ Cf,                       // mode 1: CAT row*2048 + br*1024 + col
    int mode) {
  int i = blockIdx.x * 256 + threadIdx.x;   // quad index over 2*MROWS*D/4
  int e = i * 4;
  const int per_br = MROWS * D_;
  int br = e / per_br;
  int rem = e - br * per_br;
  int row = rem >> 10;
  int col = rem & 1023;
  float4 s = {0.f, 0.f, 0.f, 0.f};
#pragma unroll
  for (int ks = 0; ks < 4; ++ks) {
    float4 v = *reinterpret_cast<const float4*>(
        P + ((size_t)(br * 4 + ks) * MROWS + row) * D_ + col);
    s.x += v.x; s.y += v.y; s.z += v.z; s.w += v.w;
  }
  const float* bias = br ? bias1 : bias0;
  s.x += bias[col]; s.y += bias[col + 1]; s.z += bias[col + 2]; s.w += bias[col + 3];
  if (mode == 0) {
    float a[4] = {tanhf(s.x), tanhf(s.y), tanhf(s.z), tanhf(s.w)};
    size_t o = (size_t)br * per_br + (size_t)row * D_ + col;
#pragma unroll
    for (int j = 0; j < 4; ++j) {
      u16 h = f2b(a[j]);
      Oh[o + j] = h;
      Ol[o + j] = f2b(a[j] - b2f(h));
    }
  } else {
    *reinterpret_cast<float4*>(Cf + (size_t)row * 2048 + br * 1024 + col) = s;
  }
}

// ---------------- labels (tnorm inlined): out cols [2048,2080) ----------------
__global__ __launch_bounds__(64) void labels_kernel(
    const float* __restrict__ s_cat, const float* __restrict__ t_cat,
    const int* __restrict__ src_ids, float* __restrict__ out) {
  int bk = blockIdx.x, lane = threadIdx.x;
  const float* srow = s_cat + (size_t)bk * 2048;
  float np = 0.f;
  float dots[16], tsq[16];
#pragma unroll
  for (int t = 0; t < 16; ++t) { dots[t] = 0.f; tsq[t] = 0.f; }
  for (int j = lane; j < 2048; j += 64) {
    float sv = srow[j];
    np += sv * sv;
#pragma unroll
    for (int t = 0; t < 16; ++t) {
      float tv = t_cat[t * 2048 + j];
      dots[t] += sv * tv;
      tsq[t] += tv * tv;
    }
  }
  np = wredsum(np);
#pragma unroll
  for (int t = 0; t < 16; ++t) { dots[t] = wredsum(dots[t]); tsq[t] = wredsum(tsq[t]); }
  float sn = fmaxf(sqrtf(np), 1e-8f);
  float ssum = 0.f;
  float sims[16];
#pragma unroll
  for (int t = 0; t < 16; ++t) {
    float tn = fmaxf(sqrtf(tsq[t]), 1e-8f);
    sims[t] = dots[t] / (sn * tn);
    ssum += sims[t];
  }
  float scale = 0.9f / ssum;
  if (lane < 16) {
    out[(size_t)bk * OUTC + 2064 + lane] = sims[lane] * scale;
  } else if (lane < 32) {
    int t2 = lane - 16;
    out[(size_t)bk * OUTC + 2048 + t2] = (src_ids[bk] == t2) ? 0.1f : 0.f;
  }
}

// =======================================================================
extern "C" void kernel_launch(void* const* d_in, const int* in_sizes, int n_in,
                              void* d_out, int out_size, void* d_ws, size_t ws_size,
                              hipStream_t stream) {
  const float* hidden    = (const float*)d_in[0];
  const int*   span_idx  = (const int*)d_in[1];
  const float* span_mask = (const float*)d_in[2];
  const int*   span_start= (const int*)d_in[3];
  const int*   span_end  = (const int*)d_in[4];
  const int*   length    = (const int*)d_in[5];
  const float* slot_emb  = (const float*)d_in[6];
  const float* tgt       = (const float*)d_in[7];
  const int*   src_ids   = (const int*)d_in[8];
  const float* Wih_f = (const float*)d_in[9];
  const float* Whh_f = (const float*)d_in[10];
  const float* bih_f = (const float*)d_in[11];
  const float* bhh_f = (const float*)d_in[12];
  const float* Wih_b = (const float*)d_in[13];
  const float* Whh_b = (const float*)d_in[14];
  const float* bih_b = (const float*)d_in[15];
  const float* bhh_b = (const float*)d_in[16];
  const float* Wps1 = (const float*)d_in[17];
  const float* bps1 = (const float*)d_in[18];
  const float* Wps2 = (const float*)d_in[19];
  const float* bps2 = (const float*)d_in[20];
  const float* Wpc1 = (const float*)d_in[21];
  const float* bpc1 = (const float*)d_in[22];
  const float* Wpc2 = (const float*)d_in[23];
  const float* bpc2 = (const float*)d_in[24];
  float* out = (float*)d_out;

  char* p = (char*)d_ws;
  auto alloc = [&](size_t bytes) -> void* {
    void* r = (void*)p;
    p += (bytes + 255) & ~(size_t)255;
    return r;
  };
  // Xbf dead after the big GEMM; T1 aliases it (16 MB >= 4.4 MB).
  u16*   Xbf   = (u16*)alloc((size_t)XROWS * D_ * 2);                 // 16 MB
  // BIG region: G2 bf16 [8192][4096] (64 MB) lives through recurrence;
  // then Hh/Hl (67.1 MB) for attn/ctx; then P partials (17.3 MB) for MLP.
  char*  BIG   = (char*)alloc((size_t)2 * B_ * S_ * D_ * 2 + (1 << 20)); // 68.1 MB
  float* hst   = (float*)alloc((size_t)2 * NSEQ * H_ * 4);
  float* cst   = (float*)alloc((size_t)2 * NSEQ * H_ * 4);
  u16*   hbfA  = (u16*)alloc((size_t)2 * NSEQ * H_ * 2);
  u16*   hbfB  = (u16*)alloc((size_t)2 * NSEQ * H_ * 2);
  float* sf    = (float*)alloc((size_t)NSEQ * 1024 * 4);
  u16*   sfh   = (u16*)alloc((size_t)NSEQ * 1024 * 2);
  u16*   sfl   = (u16*)alloc((size_t)NSEQ * 1024 * 2);
  u16*   attn_h= (u16*)alloc((size_t)NSEQ * S_ * 2);
  u16*   attn_l= (u16*)alloc((size_t)NSEQ * S_ * 2);
  float* CAT   = (float*)alloc((size_t)MROWS * 2048 * 4);
  u16* Wih2_i = (u16*)alloc((size_t)2 * G4H * D_ * 2);   // [f;b] interleaved rows
  u16* Whhf_i = (u16*)alloc((size_t)G4H * H_ * 2);
  u16* Whhb_i = (u16*)alloc((size_t)G4H * H_ * 2);
  float* bsumf = (float*)alloc(G4H * 4);
  float* bsumb = (float*)alloc(G4H * 4);
  u16* W1sh = (u16*)alloc((size_t)D_ * D_ * 2); u16* W1sl = (u16*)alloc((size_t)D_ * D_ * 2);
  u16* W2sh = (u16*)alloc((size_t)D_ * D_ * 2); u16* W2sl = (u16*)alloc((size_t)D_ * D_ * 2);
  u16* W1ch = (u16*)alloc((size_t)D_ * D_ * 2); u16* W1cl = (u16*)alloc((size_t)D_ * D_ * 2);
  u16* W2ch = (u16*)alloc((size_t)D_ * D_ * 2); u16* W2cl = (u16*)alloc((size_t)D_ * D_ * 2);
  u16* SEh = (u16*)alloc((size_t)MROWS * D_ * 2); u16* SEl = (u16*)alloc((size_t)MROWS * D_ * 2);

  // aliases
  u16*   G2 = (u16*)BIG;                               // [8192][4096] bf16
  u16*   Hh = (u16*)BIG;                               // after recurrence
  u16*   Hl = Hh + (size_t)B_ * S_ * D_;
  float* P  = (float*)BIG;                             // after ctx: [8][528][1024] f32
  u16*   T1h = Xbf;                                    // [2][528][1024]
  u16*   T1l = Xbf + (size_t)2 * MROWS * D_;

  size_t need = (size_t)(p - (char*)d_ws);
  if (need > ws_size) {
    fprintf(stderr, "kernel_launch: ws too small, need %zu have %zu\n", need, ws_size);
    return;
  }

  auto split = [&](const float* src, u16* hi, u16* lo, int n) {
    split_kernel<<<(n + 255) / 256, 256, 0, stream>>>(src, hi, lo, n);
  };

  // weight prep
  icast_kernel<<<G4H, 256, 0, stream>>>(Wih_f, Wih2_i, D_);
  icast_kernel<<<G4H, 256, 0, stream>>>(Wih_b, Wih2_i + (size_t)G4H * D_, D_);
  icast_kernel<<<G4H, 256, 0, stream>>>(Whh_f, Whhf_i, H_);
  icast_kernel<<<G4H, 256, 0, stream>>>(Whh_b, Whhb_i, H_);
  bsum_kernel<<<8, 256, 0, stream>>>(bih_f, bhh_f, bsumf);
  bsum_kernel<<<8, 256, 0, stream>>>(bih_b, bhh_b, bsumb);
  split(Wps1, W1sh, W1sl, D_ * D_);
  split(Wps2, W2sh, W2sl, D_ * D_);
  split(Wpc1, W1ch, W1cl, D_ * D_);
  split(Wpc2, W2ch, W2cl, D_ * D_);
  split(slot_emb, SEh, SEl, NSEQ * D_);
  split(tgt, SEh + (size_t)NSEQ * D_, SEl + (size_t)NSEQ * D_, NT_ * D_);

  gather_cast_kernel<<<XROWS, 256, 0, stream>>>(hidden, span_idx, Xbf);

  // ---- one big input GEMM for both directions: G2 = Xbf @ [Wih_f; Wih_b]^T (bf16 out) ----
  {
    dim3 g(4096 / 128, XROWS / 128);
    gemm_bt_kernel<<<g, 256, 0, stream>>>(Xbf, Wih2_i, nullptr, G2, XROWS, 4096, D_, 4096);
  }

  // ---- bi-LSTM recurrence: 16 steps, both directions per launch ----
  for (int t = 0; t < L_; ++t) {
    const u16* hin = (t & 1) ? hbfA : hbfB;
    u16* hout = (t & 1) ? hbfB : hbfA;
    dim3 g(G4H / 64, NSEQ / 64, 2);
    lstm_step_kernel<<<g, 256, 0, stream>>>(hin, Whhf_i, Whhb_i, G2, bsumf, bsumb,
                                            span_mask, hst, cst, hout, sf,
                                            t, t == 0 ? 1 : 0);
  }

  // ---- slot_feats out + splits ----
  copy_sf_split_kernel<<<NSEQ, 256, 0, stream>>>(sf, out, sfh, sfl);

  // ---- hidden hi/lo split (G2 dead now; BIG becomes Hh/Hl) ----
  hsplit_kernel<<<(B_ * S_ * D_) / (4 * 256), 256, 0, stream>>>(hidden, Hh, Hl);

  // ---- attention + context (3-term split MFMA) ----
  {
    dim3 g(B_, S_ / 128);
    attn_mfma_kernel<<<g, 256, 0, stream>>>(sfh, sfl, Hh, Hl,
                                            span_start, span_end, length,
                                            attn_h, attn_l);
  }
  {
    dim3 g(B_, D_ / 128);
    ctx_mfma_kernel<<<g, 256, 0, stream>>>(attn_h, attn_l, Hh, Hl, out);
  }

  // ---- MLPs: split-K (4 slices) x 2 branches batched; Hh/Hl dead -> P aliases BIG ----
  {
    dim3 g(D_ / 64, (MROWS + 63) / 64, 8);
    dim3 rg((2 * MROWS * D_) / (4 * 256));
    // layer 1
    mlp_gemm_kernel<<<g, 256, 0, stream>>>(SEh, SEl, 0, W1sh, W1sl, W1ch, W1cl, P, MROWS);
    mlp_reduce_kernel<<<rg, 256, 0, stream>>>(P, bps1, bpc1, T1h, T1l, nullptr, 0);
    // layer 2
    mlp_gemm_kernel<<<g, 256, 0, stream>>>(T1h, T1l, MROWS * D_, W2sh, W2sl, W2ch, W2cl, P, MROWS);
    mlp_reduce_kernel<<<rg, 256, 0, stream>>>(P, bps2, bpc2, nullptr, nullptr, CAT, 1);
  }

  // ---- labels ----
  const float* t_cat = CAT + (size_t)NSEQ * 2048;
  labels_kernel<<<NSEQ, 64, 0, stream>>>(CAT, t_cat, src_ids, out);
}

// Round 5
// 633.246 us; speedup vs baseline: 3.0107x; 1.2256x over previous
//
#include <hip/hip_runtime.h>
#include <cstdio>

#define B_ 32
#define S_ 512
#define D_ 1024
#define H_ 512
#define K_ 16
#define L_ 16
#define NT_ 16
#define NSEQ 512      // B*K
#define XROWS 8192    // NSEQ*L
#define G4H 2048      // 4*H
#define OUTC 2080
#define MROWS 528     // NSEQ + NT

typedef unsigned short u16;
typedef __bf16 bf16x8 __attribute__((ext_vector_type(8)));
typedef float f32x4 __attribute__((ext_vector_type(4)));

__device__ inline u16 f2b(float f) {
  union { float f; unsigned u; } x; x.f = f;
  unsigned r = x.u + 0x7FFFu + ((x.u >> 16) & 1u);
  return (u16)(r >> 16);
}
__device__ inline float b2f(u16 h) {
  union { unsigned u; float f; } c; c.u = ((unsigned)h) << 16;
  return c.f;
}
__device__ inline float sigf(float x) { return 1.0f / (1.0f + expf(-x)); }
__device__ inline float wredsum(float v) {
#pragma unroll
  for (int off = 32; off > 0; off >>= 1) v += __shfl_xor(v, off);
  return v;
}
// async global->LDS, 16B per lane; lds dest = wave-uniform base + lane*16
__device__ inline void gl16(const u16* g, u16* l) {
  __builtin_amdgcn_global_load_lds(
      (const __attribute__((address_space(1))) unsigned int*)g,
      (__attribute__((address_space(3))) unsigned int*)l, 16, 0, 0);
}

// ---------------- split f32 -> hi+lo bf16 ----------------
__global__ __launch_bounds__(256) void split_kernel(const float* __restrict__ in,
                                                    u16* __restrict__ hi,
                                                    u16* __restrict__ lo, int n) {
  int i = blockIdx.x * 256 + threadIdx.x;
  if (i >= n) return;
  float x = in[i];
  u16 h = f2b(x);
  hi[i] = h;
  lo[i] = f2b(x - b2f(h));
}

// vectorized hidden split (n multiple of 4*256)
__global__ __launch_bounds__(256) void hsplit_kernel(const float* __restrict__ in,
                                                     u16* __restrict__ hi,
                                                     u16* __restrict__ lo) {
  size_t i = ((size_t)blockIdx.x * 256 + threadIdx.x) * 4;
  float4 v = *reinterpret_cast<const float4*>(in + i);
  float a[4] = {v.x, v.y, v.z, v.w};
#pragma unroll
  for (int j = 0; j < 4; ++j) {
    u16 h = f2b(a[j]);
    hi[i + j] = h;
    lo[i + j] = f2b(a[j] - b2f(h));
  }
}

// interleave-cast LSTM weight: out[j*4+g][k] = W[g*H+j][k]
__global__ __launch_bounds__(256) void icast_kernel(const float* __restrict__ W,
                                                    u16* __restrict__ out, int Kd) {
  int rp = blockIdx.x;
  int j = rp >> 2, g = rp & 3;
  const float* src = W + ((size_t)(g * H_ + j)) * Kd;
  u16* dst = out + (size_t)rp * Kd;
  for (int k = threadIdx.x; k < Kd; k += 256) dst[k] = f2b(src[k]);
}

// combined interleaved bias
__global__ __launch_bounds__(256) void bsum_kernel(const float* __restrict__ bih,
                                                   const float* __restrict__ bhh,
                                                   float* __restrict__ bsum) {
  int rp = blockIdx.x * 256 + threadIdx.x;
  if (rp >= G4H) return;
  int j = rp >> 2, g = rp & 3;
  bsum[rp] = bih[g * H_ + j] + bhh[g * H_ + j];
}

// ---- big input GEMM, gather fused: G2[r][c] = sum_k Hh[b(r), span(r)][k] * Wih2[c][k]
// A rows gathered via span_idx; staging via global_load_lds, linear LDS.
__global__ __launch_bounds__(256) void big_gemm_kernel(
    const u16* __restrict__ Hh, const int* __restrict__ span_idx,
    const u16* __restrict__ Wih2, u16* __restrict__ G2) {
  __shared__ u16 As[128 * 32];
  __shared__ u16 Bs[128 * 32];
  const int tid = threadIdx.x;
  const int bn = blockIdx.x * 128, bm = blockIdx.y * 128;
  const int wave = tid >> 6, lane = tid & 63;
  const int wm = (wave >> 1) * 64, wn = (wave & 1) * 64;
  const int fr = lane & 15;
  const int kg = (lane >> 4) * 8;

  const u16* asrc[2];
  const u16* bsrc[2];
  u16* adst[2];
  u16* bdst[2];
#pragma unroll
  for (int j = 0; j < 2; ++j) {
    int c = tid + 256 * j;
    int gr = bm + (c >> 2);                 // global A row (n*L+t)
    int b = gr >> 8;                        // K*L = 256 rows per batch
    int sidx = span_idx[gr];
    asrc[j] = Hh + ((size_t)(b * S_ + sidx)) * D_ + (c & 3) * 8;
    bsrc[j] = Wih2 + (size_t)(bn + (c >> 2)) * D_ + (c & 3) * 8;
    int ub = (wave * 64 + 256 * j) * 8;     // u16 offset of wave-uniform chunk base
    adst[j] = As + ub;
    bdst[j] = Bs + ub;
  }

  f32x4 acc[4][4] = {};
  for (int k0 = 0; k0 < D_; k0 += 32) {
    gl16(asrc[0] + k0, adst[0]);
    gl16(asrc[1] + k0, adst[1]);
    gl16(bsrc[0] + k0, bdst[0]);
    gl16(bsrc[1] + k0, bdst[1]);
    __syncthreads();
    bf16x8 af[4], bfr[4];
#pragma unroll
    for (int m = 0; m < 4; ++m)
      af[m] = *reinterpret_cast<const bf16x8*>(&As[(wm + m * 16 + fr) * 32 + kg]);
#pragma unroll
    for (int n = 0; n < 4; ++n)
      bfr[n] = *reinterpret_cast<const bf16x8*>(&Bs[(wn + n * 16 + fr) * 32 + kg]);
#pragma unroll
    for (int m = 0; m < 4; ++m)
#pragma unroll
      for (int n = 0; n < 4; ++n)
        acc[m][n] = __builtin_amdgcn_mfma_f32_16x16x32_bf16(af[m], bfr[n], acc[m][n], 0, 0, 0);
    __syncthreads();
  }
  const int ci = lane & 15;
  const int r0 = (lane >> 4) * 4;
#pragma unroll
  for (int m = 0; m < 4; ++m)
#pragma unroll
    for (int n = 0; n < 4; ++n) {
      int col = bn + wn + n * 16 + ci;
#pragma unroll
      for (int r = 0; r < 4; ++r) {
        int row = bm + wm + m * 16 + r0 + r;
        G2[(size_t)row * 4096 + col] = f2b(acc[m][n][r]);
      }
    }
}

// ---------------- fused recurrent GEMM + LSTM gate step (both dirs via z) ------
__global__ __launch_bounds__(256) void lstm_step_kernel(
    const u16* __restrict__ hbf_in,   // [2][NSEQ][H]
    const u16* __restrict__ Whhf, const u16* __restrict__ Whhb,
    const u16* __restrict__ G2,
    const float* __restrict__ bsumf, const float* __restrict__ bsumb,
    const float* __restrict__ mask,
    float* __restrict__ hst, float* __restrict__ cst,
    u16* __restrict__ hbf_out,
    float* __restrict__ sf,
    int t, int first) {
  __shared__ u16 As[64 * 32];
  __shared__ u16 Bs[64 * 32];
  const int tid = threadIdx.x;
  const int bz = blockIdx.z;
  const int treal = bz ? (L_ - 1 - t) : t;
  const u16* Whh = bz ? Whhb : Whhf;
  const float* bsum = bz ? bsumb : bsumf;
  const size_t sofs = (size_t)bz * NSEQ * H_;
  const int bm = blockIdx.y * 64, bn = blockIdx.x * 64;
  const int wave = tid >> 6, lane = tid & 63;
  const int wm = (wave >> 1) * 32, wn = (wave & 1) * 32;
  f32x4 acc[2][2] = {};
  const int fr = lane & 15;
  const int kg = (lane >> 4) * 8;

  if (!first) {
    const int c = tid;
    const u16* asrc = hbf_in + sofs + (size_t)(bm + (c >> 2)) * H_ + (c & 3) * 8;
    const u16* bsrc = Whh + (size_t)(bn + (c >> 2)) * H_ + (c & 3) * 8;
    u16* adst = As + wave * 512;
    u16* bdst = Bs + wave * 512;
    for (int k0 = 0; k0 < H_; k0 += 32) {
      gl16(asrc + k0, adst);
      gl16(bsrc + k0, bdst);
      __syncthreads();
      bf16x8 af[2], bfr[2];
#pragma unroll
      for (int m = 0; m < 2; ++m)
        af[m] = *reinterpret_cast<const bf16x8*>(&As[(wm + m * 16 + fr) * 32 + kg]);
#pragma unroll
      for (int n = 0; n < 2; ++n)
        bfr[n] = *reinterpret_cast<const bf16x8*>(&Bs[(wn + n * 16 + fr) * 32 + kg]);
#pragma unroll
      for (int m = 0; m < 2; ++m)
#pragma unroll
        for (int n = 0; n < 2; ++n)
          acc[m][n] = __builtin_amdgcn_mfma_f32_16x16x32_bf16(af[m], bfr[n], acc[m][n], 0, 0, 0);
      __syncthreads();
    }
  }

  const int ci = lane & 15;
  const int r0 = (lane >> 4) * 4;
  const int q = lane & 3;
#pragma unroll
  for (int m = 0; m < 2; ++m)
#pragma unroll
    for (int n = 0; n < 2; ++n) {
      int c = bn + wn + n * 16 + ci;
      int rowbase = bm + wm + m * 16 + r0;
      float val[4];
#pragma unroll
      for (int r = 0; r < 4; ++r) {
        int nrow = rowbase + r;
        float g2 = b2f(G2[((size_t)nrow * L_ + treal) * 4096 + (size_t)bz * 2048 + c]);
        val[r] = acc[m][n][r] + g2 + bsum[c];
      }
      float x1[4], x2[4], x3[4];
#pragma unroll
      for (int r = 0; r < 4; ++r) {
        x1[r] = __shfl_xor(val[r], 1);
        x2[r] = __shfl_xor(val[r], 2);
        x3[r] = __shfl_xor(x1[r], 2);
      }
      if (q == 0) {
        int j = c >> 2;
#pragma unroll
        for (int r = 0; r < 4; ++r) {
          int nrow = rowbase + r;
          float gi = val[r], gf = x1[r], gg = x2[r], go = x3[r];
          float mv = mask[nrow * L_ + treal];
          size_t sidx = sofs + (size_t)nrow * H_ + j;
          float co = first ? 0.f : cst[sidx];
          float ho = first ? 0.f : hst[sidx];
          float cn = sigf(gf) * co + sigf(gi) * tanhf(gg);
          float hn = sigf(go) * tanhf(cn);
          float hnew = mv * hn + (1.f - mv) * ho;
          float cnew = mv * cn + (1.f - mv) * co;
          hst[sidx] = hnew;
          cst[sidx] = cnew;
          hbf_out[sidx] = f2b(hnew);
          size_t fidx = (size_t)nrow * 1024 + bz * 512 + j;
          float contrib = hnew * mv;
          if (first) sf[fidx] = contrib;
          else sf[fidx] += contrib;
        }
      }
    }
}

// ---------------- slot_feats: out cols [0,1024) + hi/lo split ----------------
__global__ __launch_bounds__(256) void copy_sf_split_kernel(const float* __restrict__ sf,
                                                            float* __restrict__ out,
                                                            u16* __restrict__ sfh,
                                                            u16* __restrict__ sfl) {
  int bk = blockIdx.x;
  for (int d = threadIdx.x; d < 1024; d += 256) {
    size_t i = (size_t)bk * 1024 + d;
    float v = sf[i];
    out[(size_t)bk * OUTC + d] = v;
    u16 h = f2b(v);
    sfh[i] = h;
    sfl[i] = f2b(v - b2f(h));
  }
}

// ---------------- attn = sf_b(16x1024) . hidden_b(512x1024)^T, masked, split ----------------
__global__ __launch_bounds__(256) void attn_mfma_kernel(
    const u16* __restrict__ sfh, const u16* __restrict__ sfl,
    const u16* __restrict__ Hh, const u16* __restrict__ Hl,
    const int* __restrict__ sstart, const int* __restrict__ send,
    const int* __restrict__ len,
    u16* __restrict__ attn_h, u16* __restrict__ attn_l) {
  __shared__ u16 Bh[128 * 32];
  __shared__ u16 Bl[128 * 32];
  const int b = blockIdx.x;
  const int s0 = blockIdx.y * 128;
  const int tid = threadIdx.x;
  const int wave = tid >> 6, lane = tid & 63;
  const int fr = lane & 15;
  const int kg = (lane >> 4) * 8;
  f32x4 acc[2] = {};

  const u16* hsrc[2];
  const u16* lsrc[2];
  u16* hdst[2];
  u16* ldst[2];
#pragma unroll
  for (int j = 0; j < 2; ++j) {
    int c = tid + 256 * j;
    size_t goff = ((size_t)b * S_ + s0 + (c >> 2)) * D_ + (c & 3) * 8;
    hsrc[j] = Hh + goff;
    lsrc[j] = Hl + goff;
    int ub = (wave * 64 + 256 * j) * 8;
    hdst[j] = Bh + ub;
    ldst[j] = Bl + ub;
  }

  for (int k0 = 0; k0 < D_; k0 += 32) {
    gl16(hsrc[0] + k0, hdst[0]);
    gl16(hsrc[1] + k0, hdst[1]);
    gl16(lsrc[0] + k0, ldst[0]);
    gl16(lsrc[1] + k0, ldst[1]);
    __syncthreads();
    size_t aoff = ((size_t)b * 16 + fr) * D_ + k0 + kg;
    bf16x8 ah = *reinterpret_cast<const bf16x8*>(sfh + aoff);
    bf16x8 al = *reinterpret_cast<const bf16x8*>(sfl + aoff);
#pragma unroll
    for (int nt = 0; nt < 2; ++nt) {
      bf16x8 bh = *reinterpret_cast<const bf16x8*>(&Bh[(wave * 32 + nt * 16 + fr) * 32 + kg]);
      bf16x8 bl = *reinterpret_cast<const bf16x8*>(&Bl[(wave * 32 + nt * 16 + fr) * 32 + kg]);
      acc[nt] = __builtin_amdgcn_mfma_f32_16x16x32_bf16(ah, bh, acc[nt], 0, 0, 0);
      acc[nt] = __builtin_amdgcn_mfma_f32_16x16x32_bf16(ah, bl, acc[nt], 0, 0, 0);
      acc[nt] = __builtin_amdgcn_mfma_f32_16x16x32_bf16(al, bh, acc[nt], 0, 0, 0);
    }
    __syncthreads();
  }
  const int ln = len[b];
#pragma unroll
  for (int nt = 0; nt < 2; ++nt) {
    int s = s0 + wave * 32 + nt * 16 + (lane & 15);
#pragma unroll
    for (int r = 0; r < 4; ++r) {
      int krow = (lane >> 4) * 4 + r;
      int bk = b * 16 + krow;
      int st = sstart[bk], en = send[bk];
      bool cm = (s < st) || ((s > en) && (s < ln));
      float v = cm ? acc[nt][r] : 0.f;
      u16 h = f2b(v);
      size_t idx = (size_t)bk * S_ + s;
      attn_h[idx] = h;
      attn_l[idx] = f2b(v - b2f(h));
    }
  }
}

// ---------------- context = attn_b(16x512) . hidden_b(512x1024) -> out[.,1024+d] ----------------
__global__ __launch_bounds__(256) void ctx_mfma_kernel(
    const u16* __restrict__ attn_h, const u16* __restrict__ attn_l,
    const u16* __restrict__ Hh, const u16* __restrict__ Hl,
    float* __restrict__ out) {
  __shared__ u16 Th[128][34];   // [d][s] transposed tile
  __shared__ u16 Tl[128][34];
  const int b = blockIdx.x;
  const int d0 = blockIdx.y * 128;
  const int tid = threadIdx.x;
  const int wave = tid >> 6, lane = tid & 63;
  const int fr = lane & 15;
  const int kg = (lane >> 4) * 8;
  f32x4 acc[2] = {};

  for (int k0 = 0; k0 < S_; k0 += 32) {
#pragma unroll
    for (int pass = 0; pass < 2; ++pass) {
      int idx = pass * 256 + tid;
      int srow = idx >> 4;
      int dch = (idx & 15) * 8;
      size_t goff = ((size_t)b * S_ + k0 + srow) * D_ + d0 + dch;
      uint4 vh = *reinterpret_cast<const uint4*>(Hh + goff);
      uint4 vl = *reinterpret_cast<const uint4*>(Hl + goff);
      const u16* ph = reinterpret_cast<const u16*>(&vh);
      const u16* pl = reinterpret_cast<const u16*>(&vl);
#pragma unroll
      for (int i = 0; i < 8; ++i) {
        Th[dch + i][srow] = ph[i];
        Tl[dch + i][srow] = pl[i];
      }
    }
    __syncthreads();
    size_t aoff = ((size_t)b * 16 + fr) * S_ + k0 + kg;
    bf16x8 ah = *reinterpret_cast<const bf16x8*>(attn_h + aoff);
    bf16x8 al = *reinterpret_cast<const bf16x8*>(attn_l + aoff);
#pragma unroll
    for (int nt = 0; nt < 2; ++nt) {
      bf16x8 bh = *reinterpret_cast<const bf16x8*>(&Th[wave * 32 + nt * 16 + fr][kg]);
      bf16x8 bl = *reinterpret_cast<const bf16x8*>(&Tl[wave * 32 + nt * 16 + fr][kg]);
      acc[nt] = __builtin_amdgcn_mfma_f32_16x16x32_bf16(ah, bh, acc[nt], 0, 0, 0);
      acc[nt] = __builtin_amdgcn_mfma_f32_16x16x32_bf16(ah, bl, acc[nt], 0, 0, 0);
      acc[nt] = __builtin_amdgcn_mfma_f32_16x16x32_bf16(al, bh, acc[nt], 0, 0, 0);
    }
    __syncthreads();
  }
#pragma unroll
  for (int nt = 0; nt < 2; ++nt) {
    int d = d0 + wave * 32 + nt * 16 + (lane & 15);
#pragma unroll
    for (int r = 0; r < 4; ++r) {
      int krow = (lane >> 4) * 4 + r;
      out[((size_t)b * 16 + krow) * OUTC + 1024 + d] = acc[nt][r];
    }
  }
}

// ---------------- MLP split-K GEMM: P[z] = 3-term partials over K-slice ----------------
__global__ __launch_bounds__(256) void mlp_gemm_kernel(
    const u16* __restrict__ Ah, const u16* __restrict__ Al, int a_br_stride,
    const u16* __restrict__ B0h, const u16* __restrict__ B0l,
    const u16* __restrict__ B1h, const u16* __restrict__ B1l,
    float* __restrict__ P, int M) {
  __shared__ u16 Ash[64 * 32];
  __shared__ u16 Asl[64 * 32];
  __shared__ u16 Bsh[64 * 32];
  __shared__ u16 Bsl[64 * 32];
  const int tid = threadIdx.x;
  const int zz = blockIdx.z;
  const int br = zz >> 2, ks = zz & 3;
  const u16* Ah_ = Ah + (size_t)br * a_br_stride;
  const u16* Al_ = Al + (size_t)br * a_br_stride;
  const u16* Bh = br ? B1h : B0h;
  const u16* Bl = br ? B1l : B0l;
  const int bm = blockIdx.y * 64, bn = blockIdx.x * 64;
  const int wave = tid >> 6, lane = tid & 63;
  const int wm = (wave >> 1) * 32, wn = (wave & 1) * 32;
  f32x4 acc[2][2] = {};
  const int fr = lane & 15;
  const int kg = (lane >> 4) * 8;

  const int c = tid;
  int ga = bm + (c >> 2);
  if (ga >= M) ga = M - 1;                  // clamp; OOB rows unused in epilogue
  const u16* ahsrc = Ah_ + (size_t)ga * D_ + (c & 3) * 8;
  const u16* alsrc = Al_ + (size_t)ga * D_ + (c & 3) * 8;
  const u16* bhsrc = Bh + (size_t)(bn + (c >> 2)) * D_ + (c & 3) * 8;
  const u16* blsrc = Bl + (size_t)(bn + (c >> 2)) * D_ + (c & 3) * 8;
  u16* d0 = Ash + wave * 512;
  u16* d1 = Asl + wave * 512;
  u16* d2 = Bsh + wave * 512;
  u16* d3 = Bsl + wave * 512;

  const int kbeg = ks * 256;
  for (int k0 = kbeg; k0 < kbeg + 256; k0 += 32) {
    gl16(ahsrc + k0, d0);
    gl16(alsrc + k0, d1);
    gl16(bhsrc + k0, d2);
    gl16(blsrc + k0, d3);
    __syncthreads();
    bf16x8 afh[2], afl[2], bfh[2], bfl[2];
#pragma unroll
    for (int m = 0; m < 2; ++m) {
      afh[m] = *reinterpret_cast<const bf16x8*>(&Ash[(wm + m * 16 + fr) * 32 + kg]);
      afl[m] = *reinterpret_cast<const bf16x8*>(&Asl[(wm + m * 16 + fr) * 32 + kg]);
    }
#pragma unroll
    for (int n = 0; n < 2; ++n) {
      bfh[n] = *reinterpret_cast<const bf16x8*>(&Bsh[(wn + n * 16 + fr) * 32 + kg]);
      bfl[n] = *reinterpret_cast<const bf16x8*>(&Bsl[(wn + n * 16 + fr) * 32 + kg]);
    }
#pragma unroll
    for (int m = 0; m < 2; ++m)
#pragma unroll
      for (int n = 0; n < 2; ++n) {
        acc[m][n] = __builtin_amdgcn_mfma_f32_16x16x32_bf16(afh[m], bfh[n], acc[m][n], 0, 0, 0);
        acc[m][n] = __builtin_amdgcn_mfma_f32_16x16x32_bf16(afh[m], bfl[n], acc[m][n], 0, 0, 0);
        acc[m][n] = __builtin_amdgcn_mfma_f32_16x16x32_bf16(afl[m], bfh[n], acc[m][n], 0, 0, 0);
      }
    __syncthreads();
  }
  const int ci = lane & 15;
  const int r0 = (lane >> 4) * 4;
#pragma unroll
  for (int m = 0; m < 2; ++m)
#pragma unroll
    for (int n = 0; n < 2; ++n) {
      int col = bn + wn + n * 16 + ci;
#pragma unroll
      for (int r = 0; r < 4; ++r) {
        int row = bm + wm + m * 16 + r0 + r;
        if (row < M)
          P[((size_t)zz * MROWS + row) * D_ + col] = acc[m][n][r];
      }
    }
}

// ---------------- MLP reduce: sum 4 k-slices, +bias, (tanh+split) or f32->CAT ----
__global__ __launch_bounds__(256) void mlp_reduce_kernel(
    const float* __restrict__ P,
    const float* __restrict__ bias0, const float* __restrict__ bias1,
    u16* __restrict__ Oh, u16* __restrict__ Ol,
    float* __restrict__ Cf,
    int mode) {
  int i = blockIdx.x * 256 + threadIdx.x;
  int e = i * 4;
  const int per_br = MROWS * D_;
  int br = e / per_br;
  int rem = e - br * per_br;
  int row = rem >> 10;
  int col = rem & 1023;
  float4 s = {0.f, 0.f, 0.f, 0.f};
#pragma unroll
  for (int ks = 0; ks < 4; ++ks) {
    float4 v = *reinterpret_cast<const float4*>(
        P + ((size_t)(br * 4 + ks) * MROWS + row) * D_ + col);
    s.x += v.x; s.y += v.y; s.z += v.z; s.w += v.w;
  }
  const float* bias = br ? bias1 : bias0;
  s.x += bias[col]; s.y += bias[col + 1]; s.z += bias[col + 2]; s.w += bias[col + 3];
  if (mode == 0) {
    float a[4] = {tanhf(s.x), tanhf(s.y), tanhf(s.z), tanhf(s.w)};
    size_t o = (size_t)br * per_br + (size_t)row * D_ + col;
#pragma unroll
    for (int j = 0; j < 4; ++j) {
      u16 h = f2b(a[j]);
      Oh[o + j] = h;
      Ol[o + j] = f2b(a[j] - b2f(h));
    }
  } else {
    *reinterpret_cast<float4*>(Cf + (size_t)row * 2048 + br * 1024 + col) = s;
  }
}

// ---------------- labels (tnorm inlined): out cols [2048,2080) ----------------
__global__ __launch_bounds__(64) void labels_kernel(
    const float* __restrict__ s_cat, const float* __restrict__ t_cat,
    const int* __restrict__ src_ids, float* __restrict__ out) {
  int bk = blockIdx.x, lane = threadIdx.x;
  const float* srow = s_cat + (size_t)bk * 2048;
  float np = 0.f;
  float dots[16], tsq[16];
#pragma unroll
  for (int t = 0; t < 16; ++t) { dots[t] = 0.f; tsq[t] = 0.f; }
  for (int j = lane; j < 2048; j += 64) {
    float sv = srow[j];
    np += sv * sv;
#pragma unroll
    for (int t = 0; t < 16; ++t) {
      float tv = t_cat[t * 2048 + j];
      dots[t] += sv * tv;
      tsq[t] += tv * tv;
    }
  }
  np = wredsum(np);
#pragma unroll
  for (int t = 0; t < 16; ++t) { dots[t] = wredsum(dots[t]); tsq[t] = wredsum(tsq[t]); }
  float sn = fmaxf(sqrtf(np), 1e-8f);
  float ssum = 0.f;
  float sims[16];
#pragma unroll
  for (int t = 0; t < 16; ++t) {
    float tn = fmaxf(sqrtf(tsq[t]), 1e-8f);
    sims[t] = dots[t] / (sn * tn);
    ssum += sims[t];
  }
  float scale = 0.9f / ssum;
  if (lane < 16) {
    out[(size_t)bk * OUTC + 2064 + lane] = sims[lane] * scale;
  } else if (lane < 32) {
    int t2 = lane - 16;
    out[(size_t)bk * OUTC + 2048 + t2] = (src_ids[bk] == t2) ? 0.1f : 0.f;
  }
}

// =======================================================================
extern "C" void kernel_launch(void* const* d_in, const int* in_sizes, int n_in,
                              void* d_out, int out_size, void* d_ws, size_t ws_size,
                              hipStream_t stream) {
  const float* hidden    = (const float*)d_in[0];
  const int*   span_idx  = (const int*)d_in[1];
  const float* span_mask = (const float*)d_in[2];
  const int*   span_start= (const int*)d_in[3];
  const int*   span_end  = (const int*)d_in[4];
  const int*   length    = (const int*)d_in[5];
  const float* slot_emb  = (const float*)d_in[6];
  const float* tgt       = (const float*)d_in[7];
  const int*   src_ids   = (const int*)d_in[8];
  const float* Wih_f = (const float*)d_in[9];
  const float* Whh_f = (const float*)d_in[10];
  const float* bih_f = (const float*)d_in[11];
  const float* bhh_f = (const float*)d_in[12];
  const float* Wih_b = (const float*)d_in[13];
  const float* Whh_b = (const float*)d_in[14];
  const float* bih_b = (const float*)d_in[15];
  const float* bhh_b = (const float*)d_in[16];
  const float* Wps1 = (const float*)d_in[17];
  const float* bps1 = (const float*)d_in[18];
  const float* Wps2 = (const float*)d_in[19];
  const float* bps2 = (const float*)d_in[20];
  const float* Wpc1 = (const float*)d_in[21];
  const float* bpc1 = (const float*)d_in[22];
  const float* Wpc2 = (const float*)d_in[23];
  const float* bpc2 = (const float*)d_in[24];
  float* out = (float*)d_out;

  char* p = (char*)d_ws;
  auto alloc = [&](size_t bytes) -> void* {
    void* r = (void*)p;
    p += (bytes + 255) & ~(size_t)255;
    return r;
  };
  // BIG1: G2 bf16 [8192][4096] (64 MB), dead after recurrence -> P partials (17.3 MB)
  char*  BIG1  = (char*)alloc((size_t)XROWS * 4096 * 2);
  // BIG2: Hh/Hl bf16 splits of hidden (67.1 MB), live front to ctx
  char*  BIG2  = (char*)alloc((size_t)2 * B_ * S_ * D_ * 2);
  float* hst   = (float*)alloc((size_t)2 * NSEQ * H_ * 4);
  float* cst   = (float*)alloc((size_t)2 * NSEQ * H_ * 4);
  u16*   hbfA  = (u16*)alloc((size_t)2 * NSEQ * H_ * 2);
  u16*   hbfB  = (u16*)alloc((size_t)2 * NSEQ * H_ * 2);
  float* sf    = (float*)alloc((size_t)NSEQ * 1024 * 4);
  u16*   sfh   = (u16*)alloc((size_t)NSEQ * 1024 * 2);
  u16*   sfl   = (u16*)alloc((size_t)NSEQ * 1024 * 2);
  u16*   attn_h= (u16*)alloc((size_t)NSEQ * S_ * 2);
  u16*   attn_l= (u16*)alloc((size_t)NSEQ * S_ * 2);
  float* CAT   = (float*)alloc((size_t)MROWS * 2048 * 4);
  u16* Wih2_i = (u16*)alloc((size_t)2 * G4H * D_ * 2);
  u16* Whhf_i = (u16*)alloc((size_t)G4H * H_ * 2);
  u16* Whhb_i = (u16*)alloc((size_t)G4H * H_ * 2);
  float* bsumf = (float*)alloc(G4H * 4);
  float* bsumb = (float*)alloc(G4H * 4);
  u16* W1sh = (u16*)alloc((size_t)D_ * D_ * 2); u16* W1sl = (u16*)alloc((size_t)D_ * D_ * 2);
  u16* W2sh = (u16*)alloc((size_t)D_ * D_ * 2); u16* W2sl = (u16*)alloc((size_t)D_ * D_ * 2);
  u16* W1ch = (u16*)alloc((size_t)D_ * D_ * 2); u16* W1cl = (u16*)alloc((size_t)D_ * D_ * 2);
  u16* W2ch = (u16*)alloc((size_t)D_ * D_ * 2); u16* W2cl = (u16*)alloc((size_t)D_ * D_ * 2);
  u16* SEh = (u16*)alloc((size_t)MROWS * D_ * 2); u16* SEl = (u16*)alloc((size_t)MROWS * D_ * 2);
  u16* T1h = (u16*)alloc((size_t)2 * MROWS * D_ * 2);
  u16* T1l = (u16*)alloc((size_t)2 * MROWS * D_ * 2);

  // aliases
  u16*   G2 = (u16*)BIG1;
  float* P  = (float*)BIG1;             // after recurrence
  u16*   Hh = (u16*)BIG2;
  u16*   Hl = Hh + (size_t)B_ * S_ * D_;

  size_t need = (size_t)(p - (char*)d_ws);
  if (need > ws_size) {
    fprintf(stderr, "kernel_launch: ws too small, need %zu have %zu\n", need, ws_size);
    return;
  }

  auto split = [&](const float* src, u16* hi, u16* lo, int n) {
    split_kernel<<<(n + 255) / 256, 256, 0, stream>>>(src, hi, lo, n);
  };

  // weight prep
  icast_kernel<<<G4H, 256, 0, stream>>>(Wih_f, Wih2_i, D_);
  icast_kernel<<<G4H, 256, 0, stream>>>(Wih_b, Wih2_i + (size_t)G4H * D_, D_);
  icast_kernel<<<G4H, 256, 0, stream>>>(Whh_f, Whhf_i, H_);
  icast_kernel<<<G4H, 256, 0, stream>>>(Whh_b, Whhb_i, H_);
  bsum_kernel<<<8, 256, 0, stream>>>(bih_f, bhh_f, bsumf);
  bsum_kernel<<<8, 256, 0, stream>>>(bih_b, bhh_b, bsumb);
  split(Wps1, W1sh, W1sl, D_ * D_);
  split(Wps2, W2sh, W2sl, D_ * D_);
  split(Wpc1, W1ch, W1cl, D_ * D_);
  split(Wpc2, W2ch, W2cl, D_ * D_);
  split(slot_emb, SEh, SEl, NSEQ * D_);
  split(tgt, SEh + (size_t)NSEQ * D_, SEl + (size_t)NSEQ * D_, NT_ * D_);

  // hidden hi/lo split first (Hh feeds the gathered big GEMM + attn/ctx)
  hsplit_kernel<<<(B_ * S_ * D_) / (4 * 256), 256, 0, stream>>>(hidden, Hh, Hl);

  // ---- big input GEMM (gather fused): G2 = gather(Hh) @ [Wih_f; Wih_b]^T ----
  {
    dim3 g(4096 / 128, XROWS / 128);
    big_gemm_kernel<<<g, 256, 0, stream>>>(Hh, span_idx, Wih2_i, G2);
  }

  // ---- bi-LSTM recurrence: 16 steps, both directions per launch ----
  for (int t = 0; t < L_; ++t) {
    const u16* hin = (t & 1) ? hbfA : hbfB;
    u16* hout = (t & 1) ? hbfB : hbfA;
    dim3 g(G4H / 64, NSEQ / 64, 2);
    lstm_step_kernel<<<g, 256, 0, stream>>>(hin, Whhf_i, Whhb_i, G2, bsumf, bsumb,
                                            span_mask, hst, cst, hout, sf,
                                            t, t == 0 ? 1 : 0);
  }

  // ---- slot_feats out + splits ----
  copy_sf_split_kernel<<<NSEQ, 256, 0, stream>>>(sf, out, sfh, sfl);

  // ---- attention + context (3-term split MFMA) ----
  {
    dim3 g(B_, S_ / 128);
    attn_mfma_kernel<<<g, 256, 0, stream>>>(sfh, sfl, Hh, Hl,
                                            span_start, span_end, length,
                                            attn_h, attn_l);
  }
  {
    dim3 g(B_, D_ / 128);
    ctx_mfma_kernel<<<g, 256, 0, stream>>>(attn_h, attn_l, Hh, Hl, out);
  }

  // ---- MLPs: split-K (4 slices) x 2 branches batched; G2 dead -> P aliases BIG1 ----
  {
    dim3 g(D_ / 64, (MROWS + 63) / 64, 8);
    dim3 rg((2 * MROWS * D_) / (4 * 256));
    mlp_gemm_kernel<<<g, 256, 0, stream>>>(SEh, SEl, 0, W1sh, W1sl, W1ch, W1cl, P, MROWS);
    mlp_reduce_kernel<<<rg, 256, 0, stream>>>(P, bps1, bpc1, T1h, T1l, nullptr, 0);
    mlp_gemm_kernel<<<g, 256, 0, stream>>>(T1h, T1l, MROWS * D_, W2sh, W2sl, W2ch, W2cl, P, MROWS);
    mlp_reduce_kernel<<<rg, 256, 0, stream>>>(P, bps2, bpc2, nullptr, nullptr, CAT, 1);
  }

  // ---- labels ----
  const float* t_cat = CAT + (size_t)NSEQ * 2048;
  labels_kernel<<<NSEQ, 64, 0, stream>>>(CAT, t_cat, src_ids, out);
}